// Round 10
// baseline (339.104 us; speedup 1.0000x reference)
//
#include <hip/hip_runtime.h>
#include <cstdint>

typedef unsigned short u16;
using bf16x8 = __attribute__((ext_vector_type(8))) short;   // 8 bf16 = 4 VGPR
using f32x4  = __attribute__((ext_vector_type(4))) float;   // MFMA acc

struct alignas(16) V16 { uint32_t a, b, c, d; };            // 16B chunk
struct alignas(8)  U16x4 { u16 a, b, c, d; };
struct alignas(16) F4 { float x, y, z, w; };

__device__ __forceinline__ u16 f2bf(float f) {              // RNE f32->bf16
  uint32_t u = __float_as_uint(f);
  u += 0x7fffu + ((u >> 16) & 1u);
  return (u16)(u >> 16);
}
__device__ __forceinline__ float bf2f(u16 h) {
  return __uint_as_float(((uint32_t)h) << 16);
}

// async global->LDS, 16B per lane; dest = wave-uniform base + lane*16 (linear)
#define GLOAD16(g, l) __builtin_amdgcn_global_load_lds(                         \
    (const __attribute__((address_space(1))) uint32_t*)(g),                     \
    (__attribute__((address_space(3))) uint32_t*)(l), 16, 0, 0)

// ===========================================================================
// Counted-vmcnt overlap conv-GEMM: BM=BN=256, BK=64 slab, 8 waves (2M x 4N),
// per-wave 128x64 (acc[8][4]). r9 structure (NO intra-slab fences; compiler
// interleaves ds_read<->MFMA with counted lgkmcnt) + asymmetric ring:
//   A = weights (3.4MB, L2-hot, ~250cy)  -> ring-2, prefetch distance 1
//   B = activations (50MB, L3/HBM ~900cy) -> ring-3, prefetch distance 2
// LDS = 2x32KB (A) + 3x32KB (B) = 160 KiB exactly.
// Slab boundary waits vmcnt(4): FIFO holds [B(s+1) (issued slab s-1),
// A(s+1) (k-half 0 of s), B(s+2) (k-half 1 of s)]; waiting "leave 4" proves
// A(s+1)+B(s+1) landed while B(s+2) stays in flight (T4: never drain to 0
// in steady state). Tail: vmcnt(0) only on the last 2 slabs.
// Swizzle: 128-B rows, chunk ^= (row&7) (verified 0-conflict r4/r6/r8/r9),
// applied on global SOURCE + ds_read side; gload_lds dest linear (rule #21).
// ===========================================================================
template<int MODE>
__global__ __launch_bounds__(512, 2) void gemmCnt_bf16(
    const u16* __restrict__ A, const u16* __restrict__ B, u16* __restrict__ otr,
    int sA, int sB, int64_t bBatch, int trStride, int64_t trBatch, int MT,
    const u16* __restrict__ zpage)
{
  constexpr int NS = (MODE == 2) ? 36 : 12;    // BK=64 slabs: NTAPS*(256/64)
  __shared__ __align__(16) u16 lds[81920];     // 160 KiB: A ring-2 | B ring-3
  u16* ldsB = lds + 32768;                     // B base after 2 A slabs

  const int tid = threadIdx.x;
  // XCD-aware bijective swizzle (gridDim.x % 8 == 0)
  const int q = gridDim.x >> 3;
  const int flat = (blockIdx.x & 7) * q + (blockIdx.x >> 3);
  const int per_b = MT * 16;                   // 16 n-tiles of 256
  const int b = flat / per_b, rem = flat % per_b;
  const int ntile = rem / MT, mtile = rem % MT;
  const int m0 = mtile * 256, n0 = ntile * 256;
  const u16* Bb = B + (int64_t)b * bBatch;

  const int lane = tid & 63, wave = tid >> 6;
  const int wm = wave >> 2, wn = wave & 3;     // 2M x 4N waves, 128x64 each
  const int lr = lane & 15, lc = lane >> 4;

  // staging: load (wave w, j) fills 8 rows w*32+j*8..+7, contiguous 1KB.
  const int srow = wave * 32 + (lane >> 3);    // base row (j adds 8)
  const int sch  = lane & 7;
  const int scs  = sch ^ (srow & 7);           // (srow+8j)&7 == srow&7
  const u16* aSrc[4];
  const u16* bSrc[4];
  int bRow[4];
#pragma unroll
  for (int j = 0; j < 4; ++j) {
    aSrc[j] = A + (int64_t)(m0 + srow + j * 8) * sA + scs * 8;
    bSrc[j] = Bb + (int64_t)(n0 + srow + j * 8) * sB + scs * 8;
    bRow[j] = n0 + srow + j * 8;
  }
  const int wdst = wave * 2048;                // u16; + j*512 per load

  auto stageA = [&](int s) {                   // 4 loads/thread, ring-2
    const int kOff = (s >> 2) * 256 + ((s & 3) << 6);
    u16* dst = lds + (s & 1) * 16384 + wdst;
#pragma unroll
    for (int j = 0; j < 4; ++j)
      GLOAD16(aSrc[j] + kOff, dst + j * 512);
  };
  auto stageB = [&](int s) {                   // 4 loads/thread, ring-3
    const int tap = s >> 2, kc = (s & 3) << 6;
    int off, dh = 0, dw = 0;
    if constexpr (MODE == 2) { dh = tap / 3 - 1; dw = tap % 3 - 1; off = dh * 64 + dw; }
    else                     { off = tap - 1; }
    u16* dst = ldsB + (s % 3) * 16384 + wdst;
#pragma unroll
    for (int j = 0; j < 4; ++j) {
      bool ok;
      if constexpr (MODE == 2) {
        int hh = (bRow[j] >> 6) + dh, ww = (bRow[j] & 63) + dw;
        ok = ((unsigned)hh < 64u) && ((unsigned)ww < 64u);
      } else {
        ok = ((unsigned)(bRow[j] + off) < 4096u);
      }
      const u16* src = ok ? (bSrc[j] + (int64_t)off * sB + kc) : zpage;
      GLOAD16(src, dst + j * 512);
    }
  };

  f32x4 acc[8][4];
#pragma unroll
  for (int i = 0; i < 8; ++i)
#pragma unroll
    for (int j = 0; j < 4; ++j) acc[i][j] = f32x4{0.f, 0.f, 0.f, 0.f};

  // prologue: A(0),B(0),A(1),B(1),B(2) = 20 loads; need first 8 -> vmcnt(12)
  stageA(0); stageB(0); stageA(1); stageB(1);
  if (NS > 2) stageB(2);
  asm volatile("s_waitcnt vmcnt(12)" ::: "memory");
  __builtin_amdgcn_s_barrier();
  __builtin_amdgcn_sched_barrier(0);

  for (int s = 0; s < NS; ++s) {
    const u16* As = lds + (s & 1) * 16384;
    const u16* Bs = ldsB + (s % 3) * 16384;
    bf16x8 bfr[4], af[4], af2[4];

    // ---- k-half 0: stage A(s+1) early; reads; 32 MFMA (compiler-interleaved)
    if (s + 1 < NS) stageA(s + 1);
#pragma unroll
    for (int nf = 0; nf < 4; ++nf) {
      int row = wn * 64 + nf * 16 + lr;
      bfr[nf] = *(const bf16x8*)&Bs[row * 64 + ((lc ^ (row & 7)) * 8)];
    }
#pragma unroll
    for (int mf = 0; mf < 4; ++mf) {
      int row = wm * 128 + mf * 16 + lr;
      af[mf] = *(const bf16x8*)&As[row * 64 + ((lc ^ (row & 7)) * 8)];
    }
#pragma unroll
    for (int mf = 0; mf < 4; ++mf) {
      int row = wm * 128 + 64 + mf * 16 + lr;
      af2[mf] = *(const bf16x8*)&As[row * 64 + ((lc ^ (row & 7)) * 8)];
    }
#pragma unroll
    for (int mf = 0; mf < 4; ++mf)
#pragma unroll
      for (int nf = 0; nf < 4; ++nf)
        acc[mf][nf] = __builtin_amdgcn_mfma_f32_16x16x32_bf16(af[mf], bfr[nf], acc[mf][nf], 0, 0, 0);
#pragma unroll
    for (int mf = 0; mf < 4; ++mf)
#pragma unroll
      for (int nf = 0; nf < 4; ++nf)
        acc[4 + mf][nf] = __builtin_amdgcn_mfma_f32_16x16x32_bf16(af2[mf], bfr[nf], acc[4 + mf][nf], 0, 0, 0);

    // ---- k-half 1: stage B(s+2) early; reads; 32 MFMA
    if (s + 2 < NS) stageB(s + 2);
#pragma unroll
    for (int nf = 0; nf < 4; ++nf) {
      int row = wn * 64 + nf * 16 + lr;
      bfr[nf] = *(const bf16x8*)&Bs[row * 64 + (((4 + lc) ^ (row & 7)) * 8)];
    }
#pragma unroll
    for (int mf = 0; mf < 4; ++mf) {
      int row = wm * 128 + mf * 16 + lr;
      af[mf] = *(const bf16x8*)&As[row * 64 + (((4 + lc) ^ (row & 7)) * 8)];
    }
#pragma unroll
    for (int mf = 0; mf < 4; ++mf) {
      int row = wm * 128 + 64 + mf * 16 + lr;
      af2[mf] = *(const bf16x8*)&As[row * 64 + (((4 + lc) ^ (row & 7)) * 8)];
    }
#pragma unroll
    for (int mf = 0; mf < 4; ++mf)
#pragma unroll
      for (int nf = 0; nf < 4; ++nf)
        acc[mf][nf] = __builtin_amdgcn_mfma_f32_16x16x32_bf16(af[mf], bfr[nf], acc[mf][nf], 0, 0, 0);
#pragma unroll
    for (int mf = 0; mf < 4; ++mf)
#pragma unroll
      for (int nf = 0; nf < 4; ++nf)
        acc[4 + mf][nf] = __builtin_amdgcn_mfma_f32_16x16x32_bf16(af2[mf], bfr[nf], acc[4 + mf][nf], 0, 0, 0);

    // ---- slab boundary: counted wait (leave B(s+2) in flight), barrier
    if (s + 1 < NS) {
      if (s + 2 < NS) { asm volatile("s_waitcnt vmcnt(4)" ::: "memory"); }
      else            { asm volatile("s_waitcnt vmcnt(0)" ::: "memory"); }
      __builtin_amdgcn_s_barrier();
      __builtin_amdgcn_sched_barrier(0);
    }
  }

  // epilogue: C/D layout col=lane&15, row=(lane>>4)*4+reg; write transposed
#pragma unroll
  for (int mf = 0; mf < 8; ++mf)
#pragma unroll
    for (int nf = 0; nf < 4; ++nf) {
      f32x4 v = acc[mf][nf];
      int m = m0 + wm * 128 + mf * 16 + lc * 4;
      int n = n0 + wn * 64 + nf * 16 + lr;
      U16x4 pk{f2bf(v[0]), f2bf(v[1]), f2bf(v[2]), f2bf(v[3])};
      *(U16x4*)(otr + trBatch * b + (int64_t)n * trStride + m) = pk;
    }
}

// ---------------------------------------------------------------------------
// 128x128 GEMM (dense stages: scores, y, gate, res)
// ---------------------------------------------------------------------------
template<int MODE, bool WR_RM, bool WR_TR>
__global__ __launch_bounds__(256) void gemm_bf16(
    const u16* __restrict__ A, const u16* __restrict__ B,
    float* __restrict__ orm, u16* __restrict__ otr,
    int Kc, int sA, int64_t aBatch,
    int sB, int64_t bBatch,
    int rmStride, int64_t rmBatch,
    int trStride, int64_t trBatch,
    int nsplit, int kStep, int64_t splitOut,
    const u16* __restrict__ zpage)
{
  constexpr int NTAPS = (MODE == 2) ? 9 : (MODE == 1 ? 3 : 1);
  __shared__ __align__(16) u16 As[128 * 32];
  __shared__ __align__(16) u16 Bs[128 * 32];

  const int tid = threadIdx.x;
  int b = blockIdx.z, split = 0;
  if (nsplit > 1) { split = b % nsplit; b /= nsplit; }
  const int m0  = blockIdx.y * 128;
  const int n0  = blockIdx.x * 128;
  const int lane = tid & 63, wave = tid >> 6;
  const int wm = wave >> 1, wn = wave & 1;
  const int lr = lane & 15, lc = lane >> 4;

  f32x4 acc[4][4];
#pragma unroll
  for (int i = 0; i < 4; ++i)
#pragma unroll
    for (int j = 0; j < 4; ++j) acc[i][j] = f32x4{0.f, 0.f, 0.f, 0.f};

  const u16* Ab = A + (int64_t)b * aBatch + split * kStep;
  const u16* Bb = B + (int64_t)b * bBatch + split * kStep;

  const int srow = tid >> 2;
  const int sc   = tid & 3;
  const int scs  = sc ^ (srow & 3);

  for (int t = 0; t < NTAPS; ++t) {
    int dh = 0, dw = 0, off = 0;
    if constexpr (MODE == 2) { dh = t / 3 - 1; dw = t % 3 - 1; off = dh * 64 + dw; }
    if constexpr (MODE == 1) { off = t - 1; }

    for (int kc = 0; kc < Kc; kc += 32) {
      const int kA = t * Kc + kc;
#pragma unroll
      for (int it = 0; it < 2; ++it) {
        int row = srow + it * 64;
        GLOAD16(Ab + (int64_t)(m0 + row) * sA + kA + scs * 8,
                &As[wave * 512 + it * 2048]);
      }
#pragma unroll
      for (int it = 0; it < 2; ++it) {
        int row = srow + it * 64;
        int l = n0 + row;
        int gl = l + off;
        bool ok = true;
        if constexpr (MODE == 2) {
          int hh = (l >> 6) + dh, ww = (l & 63) + dw;
          ok = ((unsigned)hh < 64u) && ((unsigned)ww < 64u);
        }
        if constexpr (MODE == 1) { ok = ((unsigned)gl < 4096u); }
        const u16* src = ok ? (Bb + (int64_t)gl * sB + kc + scs * 8) : zpage;
        GLOAD16(src, &Bs[wave * 512 + it * 2048]);
      }
      __syncthreads();

      bf16x8 af[4], bfr[4];
#pragma unroll
      for (int mf = 0; mf < 4; ++mf) {
        int row = wm * 64 + mf * 16 + lr;
        int cs = lc ^ (row & 3);
        af[mf] = *(const bf16x8*)&As[row * 32 + cs * 8];
      }
#pragma unroll
      for (int nf = 0; nf < 4; ++nf) {
        int row = wn * 64 + nf * 16 + lr;
        int cs = lc ^ (row & 3);
        bfr[nf] = *(const bf16x8*)&Bs[row * 32 + cs * 8];
      }
#pragma unroll
      for (int mf = 0; mf < 4; ++mf)
#pragma unroll
        for (int nf = 0; nf < 4; ++nf)
          acc[mf][nf] = __builtin_amdgcn_mfma_f32_16x16x32_bf16(af[mf], bfr[nf], acc[mf][nf], 0, 0, 0);
      __syncthreads();
    }
  }

#pragma unroll
  for (int mf = 0; mf < 4; ++mf) {
#pragma unroll
    for (int nf = 0; nf < 4; ++nf) {
      f32x4 v = acc[mf][nf];
      int m = m0 + wm * 64 + mf * 16 + lc * 4;
      int n = n0 + wn * 64 + nf * 16 + lr;
      if constexpr (WR_RM) {
        float* p = orm + splitOut * split + rmBatch * b + (int64_t)m * rmStride + n;
#pragma unroll
        for (int r = 0; r < 4; ++r) p[(int64_t)r * rmStride] = v[r];
      }
      if constexpr (WR_TR) {
        U16x4 pk{f2bf(v[0]), f2bf(v[1]), f2bf(v[2]), f2bf(v[3])};
        *(U16x4*)(otr + trBatch * b + (int64_t)n * trStride + m) = pk;
      }
    }
  }
}

// ---------------------------------------------------------------------------
// weight converts + zero page
// ---------------------------------------------------------------------------
__global__ void k_zero4(uint32_t* __restrict__ p) { p[threadIdx.x] = 0u; }

__global__ void k_conv_wqkv(const float* __restrict__ w, u16* __restrict__ o) {
  int idx = blockIdx.x * 256 + threadIdx.x;           // 768*2304
  if (idx >= 768 * 2304) return;
  int oc = idx / 2304, r = idx % 2304;
  int t = r >> 8, ic = r & 255;
  int kh = t / 3, kw = t % 3;
  o[idx] = f2bf(w[((oc * 256 + ic) * 3 + kh) * 3 + kw]);
}
__global__ void k_conv_wmod(const float* __restrict__ w, u16* __restrict__ o) {
  int idx = blockIdx.x * 256 + threadIdx.x;           // 512*768
  if (idx >= 512 * 768) return;
  int oc = idx / 768, r = idx % 768;
  int t = r >> 8, ic = r & 255;
  o[idx] = f2bf(w[(oc * 256 + ic) * 3 + t]);
}
__global__ void k_convert(const float* __restrict__ in, u16* __restrict__ o, int n) {
  int idx = blockIdx.x * 256 + threadIdx.x;
  if (idx < n) o[idx] = f2bf(in[idx]);
}

// ---------------------------------------------------------------------------
// x (B,256,4096) f32 -> ycatT[b][l][256+c] bf16 (x part of concat buffer)
// ---------------------------------------------------------------------------
__global__ __launch_bounds__(256) void k_xT(const float* __restrict__ x, u16* __restrict__ ycat) {
  __shared__ float tile[64 * 68];
  int b = blockIdx.z, c0 = blockIdx.y * 64, l0 = blockIdx.x * 64;
  int t = threadIdx.x;
  int cc = t >> 2, part = t & 3;
  const float* xp = x + ((int64_t)(b * 256 + c0 + cc)) * 4096 + l0 + part * 16;
#pragma unroll
  for (int j = 0; j < 4; ++j) {
    F4 v = *(const F4*)(xp + j * 4);
    float* tp = &tile[cc * 68 + part * 16 + j * 4];
    tp[0] = v.x; tp[1] = v.y; tp[2] = v.z; tp[3] = v.w;
  }
  __syncthreads();
  int l = t >> 2;
  u16* op = ycat + ((int64_t)b * 4096 + l0 + l) * 512 + 256 + c0 + part * 16;
  __align__(16) u16 tmp[16];
#pragma unroll
  for (int j = 0; j < 16; ++j) tmp[j] = f2bf(tile[(part * 16 + j) * 68 + l]);
  *(V16*)(op) = *(V16*)&tmp[0];
  *(V16*)(op + 8) = *(V16*)&tmp[8];
}

// ---------------------------------------------------------------------------
// m_q / m_k softmax, split over L (3 kernels)
// ---------------------------------------------------------------------------
__global__ __launch_bounds__(256) void k_mod_statsA(
    const u16* __restrict__ qkvT, const u16* __restrict__ modT,
    float2* __restrict__ part)
{
  int cg = blockIdx.x, ls = blockIdx.y;
  int b = blockIdx.z >> 1, sel = blockIdx.z & 1;
  int coff = cg * 32 + (sel ? 256 : 0);
  const u16* qp = qkvT + (int64_t)b * 4096 * 768 + coff;
  const u16* mp = modT + (int64_t)b * 4096 * 512 + coff;
  int t = threadIdx.x;
  int li = t >> 5, ci = t & 31;
  int l0 = ls * 512;
  float mmax = -3.4e38f, ssum = 0.f;
  for (int l = l0 + li; l < l0 + 512; l += 8) {
    float q = bf2f(qp[(int64_t)l * 768 + ci]);
    float m = bf2f(mp[(int64_t)l * 512 + ci]);
    float z = q * m; z = z > 0.f ? -z : 0.f;
    float nm = fmaxf(mmax, z);
    ssum = ssum * __expf(mmax - nm) + __expf(z - nm);
    mmax = nm;
  }
  __shared__ float sm[256], ssh[256];
  sm[t] = mmax; ssh[t] = ssum;
  __syncthreads();
  if (t < 32) {
    float M = sm[t], S = ssh[t];
#pragma unroll
    for (int k = 1; k < 8; ++k) {
      float m2 = sm[k * 32 + t], s2 = ssh[k * 32 + t];
      float nm = fmaxf(M, m2);
      S = S * __expf(M - nm) + s2 * __expf(m2 - nm);
      M = nm;
    }
    part[((int64_t)(b * 2 + sel) * 256 + cg * 32 + t) * 8 + ls] = make_float2(M, S);
  }
}

__global__ void k_mod_statsB(const float2* __restrict__ part, float2* __restrict__ fin) {
  int idx = blockIdx.x * 256 + threadIdx.x;   // 4096 channels
  float M = -3.4e38f, S = 0.f;
#pragma unroll
  for (int s = 0; s < 8; ++s) {
    float2 v = part[(int64_t)idx * 8 + s];
    float nm = fmaxf(M, v.x);
    S = S * __expf(M - nm) + v.y * __expf(v.x - nm);
    M = nm;
  }
  fin[idx] = make_float2(M, 1.0f / S);
}

__global__ __launch_bounds__(256) void k_mod_normC(
    const u16* __restrict__ qkvT, const u16* __restrict__ modT,
    const float2* __restrict__ fin, u16* __restrict__ mq, u16* __restrict__ mk)
{
  int cg = blockIdx.x, ls = blockIdx.y;
  int b = blockIdx.z >> 1, sel = blockIdx.z & 1;
  int coff = cg * 32 + (sel ? 256 : 0);
  const u16* qp = qkvT + (int64_t)b * 4096 * 768 + coff;
  const u16* mp = modT + (int64_t)b * 4096 * 512 + coff;
  u16* out = (sel ? mk : mq) + ((int64_t)b * 256 + cg * 32) * 4096;

  __shared__ float zt[64 * 33];
  int t = threadIdx.x;
  int lrow = t >> 2, part4 = t & 3;
  int co = t >> 3, lw = t & 7;
  float2 ms = fin[(int64_t)(b * 2 + sel) * 256 + cg * 32 + co];
  float Mv = ms.x, inv = ms.y;
  int lbase = ls * 512;
  for (int l0 = lbase; l0 < lbase + 512; l0 += 64) {
    V16 qv = *(const V16*)(qp + (int64_t)(l0 + lrow) * 768 + part4 * 8);
    V16 mv = *(const V16*)(mp + (int64_t)(l0 + lrow) * 512 + part4 * 8);
    const u16* qu = (const u16*)&qv;
    const u16* mu = (const u16*)&mv;
#pragma unroll
    for (int j = 0; j < 8; ++j) {
      float z = bf2f(qu[j]) * bf2f(mu[j]);
      zt[lrow * 33 + part4 * 8 + j] = z > 0.f ? -z : 0.f;
    }
    __syncthreads();
    __align__(16) u16 pk[8];
#pragma unroll
    for (int j = 0; j < 8; ++j) {
      float z = zt[(lw * 8 + j) * 33 + co];
      pk[j] = f2bf(__expf(z - Mv) * inv);
    }
    *(V16*)(out + (int64_t)co * 4096 + l0 + lw * 8) = *(V16*)&pk[0];
    __syncthreads();
  }
}

// softmax over d of (sum of split-K partials)*(1/16); block per (c,b)
__global__ __launch_bounds__(256) void k_softmax_attn(
    const float* __restrict__ sc, u16* __restrict__ ma, int nsplit, int64_t splitOff) {
  int c = blockIdx.x, b = blockIdx.y;
  int64_t base = ((int64_t)b * 256 + c) * 256;
  int t = threadIdx.x;
  float z = 0.f;
  for (int s = 0; s < nsplit; ++s) z += sc[(int64_t)s * splitOff + base + t];
  z *= 0.0625f;
  __shared__ float red[256];
  red[t] = z; __syncthreads();
  for (int s = 128; s > 0; s >>= 1) { if (t < s) red[t] = fmaxf(red[t], red[t + s]); __syncthreads(); }
  float M = red[0]; __syncthreads();
  float p = __expf(z - M);
  red[t] = p; __syncthreads();
  for (int s = 128; s > 0; s >>= 1) { if (t < s) red[t] += red[t + s]; __syncthreads(); }
  ma[base + t] = f2bf(p / red[0]);
}

// out = sigmoid(gpre)*res + (1-sigmoid(gpre))*y
__global__ __launch_bounds__(256) void k_final(const F4* __restrict__ gp, const F4* __restrict__ rs,
                                               const F4* __restrict__ yy, F4* __restrict__ o, int n4) {
  int i = blockIdx.x * 256 + threadIdx.x;
  int stride = gridDim.x * 256;
  for (; i < n4; i += stride) {
    F4 g = gp[i], r = rs[i], y = yy[i], ov;
    float gx = 1.f / (1.f + __expf(-g.x));
    float gy = 1.f / (1.f + __expf(-g.y));
    float gz = 1.f / (1.f + __expf(-g.z));
    float gw = 1.f / (1.f + __expf(-g.w));
    ov.x = gx * r.x + (1.f - gx) * y.x;
    ov.y = gy * r.y + (1.f - gy) * y.y;
    ov.z = gz * r.z + (1.f - gz) * y.z;
    ov.w = gw * r.w + (1.f - gw) * y.w;
    o[i] = ov;
  }
}

// ---------------------------------------------------------------------------
extern "C" void kernel_launch(void* const* d_in, const int* in_sizes, int n_in,
                              void* d_out, int out_size, void* d_ws, size_t ws_size,
                              hipStream_t stream) {
  (void)in_sizes; (void)n_in; (void)out_size; (void)ws_size;
  const float* x      = (const float*)d_in[0];
  const float* w_qkv  = (const float*)d_in[1];
  const float* w_mod  = (const float*)d_in[2];
  const float* w_res  = (const float*)d_in[3];
  const float* w_gate = (const float*)d_in[4];
  float* out = (float*)d_out;

  char* p = (char*)d_ws;
  auto take = [&](size_t n) { void* r = (void*)p; p += (n + 255) & ~(size_t)255; return r; };
  u16*    zpage  = (u16*)take(256);        // zero page for masked conv taps
  u16*    qkvT   = (u16*)take(50331648);   // [b][l][768] bf16 (q|k|v)
  u16*    modT   = (u16*)take(33554432);   // [b][l][512] bf16 (qm|km)
  u16*    ycatT  = (u16*)take(33554432);   // [b][l][512] bf16 (y|x)
  u16*    mq     = (u16*)take(16777216);   // [b][c][l] bf16
  u16*    mk     = (u16*)take(16777216);   // [b][d][l] bf16 (contiguous after mq)
  float*  scores = (float*)take(16777216); // [8 splits][b][c][d] f32
  u16*    mattn  = (u16*)take(1048576);    // [b][c][d] bf16
  float*  yb     = (float*)take(33554432); // [b][c][l] f32
  float2* partMS = (float2*)take(262144);  // [b*sel*c][8 lsplit] (M,S)
  float2* finMS  = (float2*)take(32768);   // [b*sel*c] (M, 1/S)
  u16*    Wa     = (u16*)take(3538944);    // 768 x 2304
  u16*    Wb     = (u16*)take(786432);     // 512 x 768
  u16*    Wg     = (u16*)take(262144);     // 256 x 512
  u16*    Wr     = (u16*)take(131072);     // 256 x 256
  float* gpre = (float*)modT;              // alias: modT dead after mod softmax
  float* resb = (float*)mq;                // alias: mq/mk dead after scores GEMM

  k_zero4<<<1, 64, 0, stream>>>((uint32_t*)zpage);
  k_conv_wqkv<<<6912, 256, 0, stream>>>(w_qkv, Wa);
  k_conv_wmod<<<1536, 256, 0, stream>>>(w_mod, Wb);
  k_convert<<<512, 256, 0, stream>>>(w_gate, Wg, 131072);
  k_convert<<<256, 256, 0, stream>>>(w_res, Wr, 65536);
  k_xT<<<dim3(64, 4, 8), 256, 0, stream>>>(x, ycatT);

  // qkv = conv2d(x, w_qkv): M=768 N=4096 K=9*256 -> qkvT bf16 (counted-vmcnt)
  gemmCnt_bf16<2><<<384, 512, 0, stream>>>(
      Wa, ycatT + 256, qkvT,
      2304, 512, (int64_t)4096 * 512,
      768, (int64_t)4096 * 768, 3, zpage);

  // mod = conv1d(v, w_mod): M=512 N=4096 K=3*256 -> modT bf16 (counted-vmcnt)
  gemmCnt_bf16<1><<<256, 512, 0, stream>>>(
      Wb, qkvT + 512, modT,
      768, 768, (int64_t)4096 * 768,
      512, (int64_t)4096 * 512, 2, zpage);

  // m_q/m_k softmax, L-split x8 for occupancy
  k_mod_statsA<<<dim3(8, 8, 16), 256, 0, stream>>>(qkvT, modT, partMS);
  k_mod_statsB<<<16, 256, 0, stream>>>(partMS, finMS);
  k_mod_normC<<<dim3(8, 8, 16), 256, 0, stream>>>(qkvT, modT, finMS, mq, mk);

  // scores[c][d] = sum_l mq[c,l]*mk[d,l]: M=256 N=256 K=4096, split-K x8
  gemm_bf16<0, true, false><<<dim3(2, 2, 64), 256, 0, stream>>>(
      mq, mk, scores, nullptr,
      512, 4096, (int64_t)256 * 4096,
      4096, (int64_t)256 * 4096,
      256, (int64_t)256 * 256,
      0, 0,
      8, 512, (int64_t)8 * 256 * 256, zpage);

  k_softmax_attn<<<dim3(256, 8), 256, 0, stream>>>(scores, mattn, 8, (int64_t)8 * 256 * 256);

  // y = m_attn @ v: M=256 N=4096 K=256 -> yb f32 + ycatT[:,0:256] bf16
  gemm_bf16<0, true, true><<<dim3(32, 2, 8), 256, 0, stream>>>(
      mattn, qkvT + 512, yb, ycatT,
      256, 256, (int64_t)256 * 256,
      768, (int64_t)4096 * 768,
      4096, (int64_t)256 * 4096,
      512, (int64_t)4096 * 512,
      1, 0, 0, zpage);

  // gpre = w_gate @ [y;x]: M=256 N=4096 K=512
  gemm_bf16<0, true, false><<<dim3(32, 2, 8), 256, 0, stream>>>(
      Wg, ycatT, gpre, nullptr,
      512, 512, 0,
      512, (int64_t)4096 * 512,
      4096, (int64_t)256 * 4096,
      0, 0,
      1, 0, 0, zpage);

  // res = w_res @ x: M=256 N=4096 K=256
  gemm_bf16<0, true, false><<<dim3(32, 2, 8), 256, 0, stream>>>(
      Wr, ycatT + 256, resb, nullptr,
      256, 256, 0,
      512, (int64_t)4096 * 512,
      4096, (int64_t)256 * 4096,
      0, 0,
      1, 0, 0, zpage);

  k_final<<<2048, 256, 0, stream>>>((const F4*)gpre, (const F4*)resb, (const F4*)yb, (F4*)out, 2097152);
}

// Round 11
// 303.600 us; speedup vs baseline: 1.1169x; 1.1169x over previous
//
#include <hip/hip_runtime.h>
#include <cstdint>

typedef unsigned short u16;
using bf16x8 = __attribute__((ext_vector_type(8))) short;   // 8 bf16 = 4 VGPR
using f32x4  = __attribute__((ext_vector_type(4))) float;   // MFMA acc

struct alignas(16) V16 { uint32_t a, b, c, d; };            // 16B chunk
struct alignas(8)  U16x4 { u16 a, b, c, d; };
struct alignas(16) F4 { float x, y, z, w; };

__device__ __forceinline__ u16 f2bf(float f) {              // RNE f32->bf16
  uint32_t u = __float_as_uint(f);
  u += 0x7fffu + ((u >> 16) & 1u);
  return (u16)(u >> 16);
}
__device__ __forceinline__ float bf2f(u16 h) {
  return __uint_as_float(((uint32_t)h) << 16);
}

// async global->LDS, 16B per lane; dest = wave-uniform base + lane*16 (linear)
#define GLOAD16(g, l) __builtin_amdgcn_global_load_lds(                         \
    (const __attribute__((address_space(1))) uint32_t*)(g),                     \
    (__attribute__((address_space(3))) uint32_t*)(l), 16, 0, 0)

// ===========================================================================
// Overlap-pipelined conv-GEMM (r9, best measured: 873 TF conv2d):
// BM=BN=256, BK=64 slab, 8 waves (2M x 4N), per-wave 128x64 (acc[8][4]).
// NO intra-slab fences -> compiler interleaves ds_read<->MFMA with counted
// lgkmcnt. LDS ring-2 dbuf 128 KiB; boundary = vmcnt(0)+barrier per slab.
// Swizzle: 128-B rows, chunk ^= (row&7) (0-conflict, r4/r6/r8/r9), applied
// on global SOURCE + ds_read side; gload_lds dest linear (rule #21).
// ===========================================================================
template<int MODE>
__global__ __launch_bounds__(512, 2) void gemmOv_bf16(
    const u16* __restrict__ A, const u16* __restrict__ B, u16* __restrict__ otr,
    int sA, int sB, int64_t bBatch, int trStride, int64_t trBatch, int MT,
    const u16* __restrict__ zpage)
{
  constexpr int NS = (MODE == 2) ? 36 : 12;    // BK=64 slabs: NTAPS*(256/64)
  __shared__ __align__(16) u16 lds[65536];     // 128 KiB = 2 x (A32KB+B32KB)

  const int tid = threadIdx.x;
  const int q = gridDim.x >> 3;                // XCD-aware bijective swizzle
  const int flat = (blockIdx.x & 7) * q + (blockIdx.x >> 3);
  const int per_b = MT * 16;                   // 16 n-tiles of 256
  const int b = flat / per_b, rem = flat % per_b;
  const int ntile = rem / MT, mtile = rem % MT;
  const int m0 = mtile * 256, n0 = ntile * 256;
  const u16* Bb = B + (int64_t)b * bBatch;

  const int lane = tid & 63, wave = tid >> 6;
  const int wm = wave >> 2, wn = wave & 3;     // 2M x 4N waves, 128x64 each
  const int lr = lane & 15, lc = lane >> 4;

  const int srow = wave * 32 + (lane >> 3);    // staging base row (j adds 8)
  const int sch  = lane & 7;
  const int scs  = sch ^ (srow & 7);           // (srow+8j)&7 == srow&7
  const u16* aSrc[4];
  const u16* bSrc[4];
  int bRow[4];
#pragma unroll
  for (int j = 0; j < 4; ++j) {
    aSrc[j] = A + (int64_t)(m0 + srow + j * 8) * sA + scs * 8;
    bSrc[j] = Bb + (int64_t)(n0 + srow + j * 8) * sB + scs * 8;
    bRow[j] = n0 + srow + j * 8;
  }
  const int wdst = wave * 2048;                // u16; + j*512 per load

  auto stageA = [&](int s) {                   // 4 loads/thread
    const int kOff = (s >> 2) * 256 + ((s & 3) << 6);
    u16* dst = lds + (s & 1) * 32768 + wdst;
#pragma unroll
    for (int j = 0; j < 4; ++j)
      GLOAD16(aSrc[j] + kOff, dst + j * 512);
  };
  auto stageB = [&](int s) {                   // 4 loads/thread (tap-masked)
    const int tap = s >> 2, kc = (s & 3) << 6;
    int off, dh = 0, dw = 0;
    if constexpr (MODE == 2) { dh = tap / 3 - 1; dw = tap % 3 - 1; off = dh * 64 + dw; }
    else                     { off = tap - 1; }
    u16* dst = lds + (s & 1) * 32768 + 16384 + wdst;
#pragma unroll
    for (int j = 0; j < 4; ++j) {
      bool ok;
      if constexpr (MODE == 2) {
        int hh = (bRow[j] >> 6) + dh, ww = (bRow[j] & 63) + dw;
        ok = ((unsigned)hh < 64u) && ((unsigned)ww < 64u);
      } else {
        ok = ((unsigned)(bRow[j] + off) < 4096u);
      }
      const u16* src = ok ? (bSrc[j] + (int64_t)off * sB + kc) : zpage;
      GLOAD16(src, dst + j * 512);
    }
  };

  f32x4 acc[8][4];
#pragma unroll
  for (int i = 0; i < 8; ++i)
#pragma unroll
    for (int j = 0; j < 4; ++j) acc[i][j] = f32x4{0.f, 0.f, 0.f, 0.f};

  stageA(0); stageB(0);
  asm volatile("s_waitcnt vmcnt(0)" ::: "memory");
  __builtin_amdgcn_s_barrier();
  __builtin_amdgcn_sched_barrier(0);

  for (int s = 0; s < NS; ++s) {
    const u16* As = lds + (s & 1) * 32768;
    const u16* Bs = As + 16384;
    const bool pf = (s + 1 < NS);
    bf16x8 bfr[4], af[4], af2[4];

    // ---- k-half 0: reads + stage A(s+1) + 32 MFMA (compiler-interleaved)
#pragma unroll
    for (int nf = 0; nf < 4; ++nf) {
      int row = wn * 64 + nf * 16 + lr;
      bfr[nf] = *(const bf16x8*)&Bs[row * 64 + ((lc ^ (row & 7)) * 8)];
    }
#pragma unroll
    for (int mf = 0; mf < 4; ++mf) {
      int row = wm * 128 + mf * 16 + lr;
      af[mf] = *(const bf16x8*)&As[row * 64 + ((lc ^ (row & 7)) * 8)];
    }
    if (pf) stageA(s + 1);
#pragma unroll
    for (int mf = 0; mf < 4; ++mf) {
      int row = wm * 128 + 64 + mf * 16 + lr;
      af2[mf] = *(const bf16x8*)&As[row * 64 + ((lc ^ (row & 7)) * 8)];
    }
#pragma unroll
    for (int mf = 0; mf < 4; ++mf)
#pragma unroll
      for (int nf = 0; nf < 4; ++nf)
        acc[mf][nf] = __builtin_amdgcn_mfma_f32_16x16x32_bf16(af[mf], bfr[nf], acc[mf][nf], 0, 0, 0);
#pragma unroll
    for (int mf = 0; mf < 4; ++mf)
#pragma unroll
      for (int nf = 0; nf < 4; ++nf)
        acc[4 + mf][nf] = __builtin_amdgcn_mfma_f32_16x16x32_bf16(af2[mf], bfr[nf], acc[4 + mf][nf], 0, 0, 0);

    // ---- k-half 1: reads + stage B(s+1) + 32 MFMA
#pragma unroll
    for (int nf = 0; nf < 4; ++nf) {
      int row = wn * 64 + nf * 16 + lr;
      bfr[nf] = *(const bf16x8*)&Bs[row * 64 + (((4 + lc) ^ (row & 7)) * 8)];
    }
#pragma unroll
    for (int mf = 0; mf < 4; ++mf) {
      int row = wm * 128 + mf * 16 + lr;
      af[mf] = *(const bf16x8*)&As[row * 64 + (((4 + lc) ^ (row & 7)) * 8)];
    }
    if (pf) stageB(s + 1);
#pragma unroll
    for (int mf = 0; mf < 4; ++mf) {
      int row = wm * 128 + 64 + mf * 16 + lr;
      af2[mf] = *(const bf16x8*)&As[row * 64 + (((4 + lc) ^ (row & 7)) * 8)];
    }
#pragma unroll
    for (int mf = 0; mf < 4; ++mf)
#pragma unroll
      for (int nf = 0; nf < 4; ++nf)
        acc[mf][nf] = __builtin_amdgcn_mfma_f32_16x16x32_bf16(af[mf], bfr[nf], acc[mf][nf], 0, 0, 0);
#pragma unroll
    for (int mf = 0; mf < 4; ++mf)
#pragma unroll
      for (int nf = 0; nf < 4; ++nf)
        acc[4 + mf][nf] = __builtin_amdgcn_mfma_f32_16x16x32_bf16(af2[mf], bfr[nf], acc[4 + mf][nf], 0, 0, 0);

    if (pf) {
      asm volatile("s_waitcnt vmcnt(0)" ::: "memory");
      __builtin_amdgcn_s_barrier();
      __builtin_amdgcn_sched_barrier(0);
    }
  }

  // epilogue: C/D layout col=lane&15, row=(lane>>4)*4+reg; write transposed
#pragma unroll
  for (int mf = 0; mf < 8; ++mf)
#pragma unroll
    for (int nf = 0; nf < 4; ++nf) {
      f32x4 v = acc[mf][nf];
      int m = m0 + wm * 128 + mf * 16 + lc * 4;
      int n = n0 + wn * 64 + nf * 16 + lr;
      U16x4 pk{f2bf(v[0]), f2bf(v[1]), f2bf(v[2]), f2bf(v[3])};
      *(U16x4*)(otr + trBatch * b + (int64_t)n * trStride + m) = pk;
    }
}

// ---------------------------------------------------------------------------
// 128x128 GEMM (dense stages: scores, y, res, gate[+fused sigmoid blend])
// ---------------------------------------------------------------------------
template<int MODE, bool WR_RM, bool WR_TR, bool WR_FOUT = false>
__global__ __launch_bounds__(256) void gemm_bf16(
    const u16* __restrict__ A, const u16* __restrict__ B,
    float* __restrict__ orm, u16* __restrict__ otr,
    int Kc, int sA, int64_t aBatch,
    int sB, int64_t bBatch,
    int rmStride, int64_t rmBatch,
    int trStride, int64_t trBatch,
    int nsplit, int kStep, int64_t splitOut,
    const u16* __restrict__ zpage,
    const float* __restrict__ frs, const float* __restrict__ fyy)
{
  constexpr int NTAPS = (MODE == 2) ? 9 : (MODE == 1 ? 3 : 1);
  __shared__ __align__(16) u16 As[128 * 32];
  __shared__ __align__(16) u16 Bs[128 * 32];

  const int tid = threadIdx.x;
  int b = blockIdx.z, split = 0;
  if (nsplit > 1) { split = b % nsplit; b /= nsplit; }
  const int m0  = blockIdx.y * 128;
  const int n0  = blockIdx.x * 128;
  const int lane = tid & 63, wave = tid >> 6;
  const int wm = wave >> 1, wn = wave & 1;
  const int lr = lane & 15, lc = lane >> 4;

  f32x4 acc[4][4];
#pragma unroll
  for (int i = 0; i < 4; ++i)
#pragma unroll
    for (int j = 0; j < 4; ++j) acc[i][j] = f32x4{0.f, 0.f, 0.f, 0.f};

  const u16* Ab = A + (int64_t)b * aBatch + split * kStep;
  const u16* Bb = B + (int64_t)b * bBatch + split * kStep;

  const int srow = tid >> 2;
  const int sc   = tid & 3;
  const int scs  = sc ^ (srow & 3);

  for (int t = 0; t < NTAPS; ++t) {
    int dh = 0, dw = 0, off = 0;
    if constexpr (MODE == 2) { dh = t / 3 - 1; dw = t % 3 - 1; off = dh * 64 + dw; }
    if constexpr (MODE == 1) { off = t - 1; }

    for (int kc = 0; kc < Kc; kc += 32) {
      const int kA = t * Kc + kc;
#pragma unroll
      for (int it = 0; it < 2; ++it) {
        int row = srow + it * 64;
        GLOAD16(Ab + (int64_t)(m0 + row) * sA + kA + scs * 8,
                &As[wave * 512 + it * 2048]);
      }
#pragma unroll
      for (int it = 0; it < 2; ++it) {
        int row = srow + it * 64;
        int l = n0 + row;
        int gl = l + off;
        bool ok = true;
        if constexpr (MODE == 2) {
          int hh = (l >> 6) + dh, ww = (l & 63) + dw;
          ok = ((unsigned)hh < 64u) && ((unsigned)ww < 64u);
        }
        if constexpr (MODE == 1) { ok = ((unsigned)gl < 4096u); }
        const u16* src = ok ? (Bb + (int64_t)gl * sB + kc + scs * 8) : zpage;
        GLOAD16(src, &Bs[wave * 512 + it * 2048]);
      }
      __syncthreads();

      bf16x8 af[4], bfr[4];
#pragma unroll
      for (int mf = 0; mf < 4; ++mf) {
        int row = wm * 64 + mf * 16 + lr;
        int cs = lc ^ (row & 3);
        af[mf] = *(const bf16x8*)&As[row * 32 + cs * 8];
      }
#pragma unroll
      for (int nf = 0; nf < 4; ++nf) {
        int row = wn * 64 + nf * 16 + lr;
        int cs = lc ^ (row & 3);
        bfr[nf] = *(const bf16x8*)&Bs[row * 32 + cs * 8];
      }
#pragma unroll
      for (int mf = 0; mf < 4; ++mf)
#pragma unroll
        for (int nf = 0; nf < 4; ++nf)
          acc[mf][nf] = __builtin_amdgcn_mfma_f32_16x16x32_bf16(af[mf], bfr[nf], acc[mf][nf], 0, 0, 0);
      __syncthreads();
    }
  }

#pragma unroll
  for (int mf = 0; mf < 4; ++mf) {
#pragma unroll
    for (int nf = 0; nf < 4; ++nf) {
      f32x4 v = acc[mf][nf];
      int m = m0 + wm * 64 + mf * 16 + lc * 4;
      int n = n0 + wn * 64 + nf * 16 + lr;
      if constexpr (WR_FOUT) {
        // out = sigmoid(gpre)*res + (1-sigmoid(gpre))*y, fused in epilogue
        int64_t off = rmBatch * b + (int64_t)m * rmStride + n;
        float* p = orm + off;
        const float* pr = frs + off;
        const float* py = fyy + off;
#pragma unroll
        for (int r = 0; r < 4; ++r) {
          float g = 1.f / (1.f + __expf(-v[r]));
          p[(int64_t)r * rmStride] =
              g * pr[(int64_t)r * rmStride] + (1.f - g) * py[(int64_t)r * rmStride];
        }
      }
      if constexpr (WR_RM) {
        float* p = orm + splitOut * split + rmBatch * b + (int64_t)m * rmStride + n;
#pragma unroll
        for (int r = 0; r < 4; ++r) p[(int64_t)r * rmStride] = v[r];
      }
      if constexpr (WR_TR) {
        U16x4 pk{f2bf(v[0]), f2bf(v[1]), f2bf(v[2]), f2bf(v[3])};
        *(U16x4*)(otr + trBatch * b + (int64_t)n * trStride + m) = pk;
      }
    }
  }
}

// ---------------------------------------------------------------------------
// weight converts + zero page
// ---------------------------------------------------------------------------
__global__ void k_zero4(uint32_t* __restrict__ p) { p[threadIdx.x] = 0u; }

__global__ void k_conv_wqkv(const float* __restrict__ w, u16* __restrict__ o) {
  int idx = blockIdx.x * 256 + threadIdx.x;           // 768*2304
  if (idx >= 768 * 2304) return;
  int oc = idx / 2304, r = idx % 2304;
  int t = r >> 8, ic = r & 255;
  int kh = t / 3, kw = t % 3;
  o[idx] = f2bf(w[((oc * 256 + ic) * 3 + kh) * 3 + kw]);
}
__global__ void k_conv_wmod(const float* __restrict__ w, u16* __restrict__ o) {
  int idx = blockIdx.x * 256 + threadIdx.x;           // 512*768
  if (idx >= 512 * 768) return;
  int oc = idx / 768, r = idx % 768;
  int t = r >> 8, ic = r & 255;
  o[idx] = f2bf(w[(oc * 256 + ic) * 3 + t]);
}
__global__ void k_convert(const float* __restrict__ in, u16* __restrict__ o, int n) {
  int idx = blockIdx.x * 256 + threadIdx.x;
  if (idx < n) o[idx] = f2bf(in[idx]);
}

// ---------------------------------------------------------------------------
// x (B,256,4096) f32 -> ycatT[b][l][256+c] bf16 (x part of concat buffer)
// ---------------------------------------------------------------------------
__global__ __launch_bounds__(256) void k_xT(const float* __restrict__ x, u16* __restrict__ ycat) {
  __shared__ float tile[64 * 68];
  int b = blockIdx.z, c0 = blockIdx.y * 64, l0 = blockIdx.x * 64;
  int t = threadIdx.x;
  int cc = t >> 2, part = t & 3;
  const float* xp = x + ((int64_t)(b * 256 + c0 + cc)) * 4096 + l0 + part * 16;
#pragma unroll
  for (int j = 0; j < 4; ++j) {
    F4 v = *(const F4*)(xp + j * 4);
    float* tp = &tile[cc * 68 + part * 16 + j * 4];
    tp[0] = v.x; tp[1] = v.y; tp[2] = v.z; tp[3] = v.w;
  }
  __syncthreads();
  int l = t >> 2;
  u16* op = ycat + ((int64_t)b * 4096 + l0 + l) * 512 + 256 + c0 + part * 16;
  __align__(16) u16 tmp[16];
#pragma unroll
  for (int j = 0; j < 16; ++j) tmp[j] = f2bf(tile[(part * 16 + j) * 68 + l]);
  *(V16*)(op) = *(V16*)&tmp[0];
  *(V16*)(op + 8) = *(V16*)&tmp[8];
}

// ---------------------------------------------------------------------------
// Mod softmax, MAX-FREE + DEFERRED NORMALIZATION:
//   z = -relu(q*qm) <= 0, so exp(z) in (0,1] -- no max subtraction needed
//   (softmax is shift-invariant; row max ~= 0 anyway). Write UNNORMALIZED
//   e = exp(z) as bf16 to mq/mk; accumulate per-channel partial sums S.
//   Normalization invSq[c]*invSk[d] is applied inside k_softmax_attn
//   (multiplicative row factor cancels... applied explicitly; exact algebra:
//   einsum(m_q,m_k) = s' * invSq[c] * invSk[d]).
// ---------------------------------------------------------------------------
__global__ __launch_bounds__(256) void k_mod_exp(
    const u16* __restrict__ qkvT, const u16* __restrict__ modT,
    u16* __restrict__ mq, u16* __restrict__ mk, float* __restrict__ partS)
{
  int cg = blockIdx.x, ls = blockIdx.y;
  int b = blockIdx.z >> 1, sel = blockIdx.z & 1;
  int coff = cg * 32 + (sel ? 256 : 0);
  const u16* qp = qkvT + (int64_t)b * 4096 * 768 + coff;
  const u16* mp = modT + (int64_t)b * 4096 * 512 + coff;
  u16* out = (sel ? mk : mq) + ((int64_t)b * 256 + cg * 32) * 4096;

  __shared__ float zt[64 * 33];
  __shared__ float rsum[256];
  int t = threadIdx.x;
  int lrow = t >> 2, part4 = t & 3;          // loader: 64 l x 32 c tile
  int co = t >> 3, lw = t & 7;               // writer: 32 c x 8 l-chunks
  float ssum = 0.f;
  int lbase = ls * 512;
  for (int l0 = lbase; l0 < lbase + 512; l0 += 64) {
    V16 qv = *(const V16*)(qp + (int64_t)(l0 + lrow) * 768 + part4 * 8);
    V16 mv = *(const V16*)(mp + (int64_t)(l0 + lrow) * 512 + part4 * 8);
    const u16* qu = (const u16*)&qv;
    const u16* mu = (const u16*)&mv;
#pragma unroll
    for (int j = 0; j < 8; ++j) {
      float z = bf2f(qu[j]) * bf2f(mu[j]);
      zt[lrow * 33 + part4 * 8 + j] = z > 0.f ? -z : 0.f;
    }
    __syncthreads();
    __align__(16) u16 pk[8];
#pragma unroll
    for (int j = 0; j < 8; ++j) {
      float e = __expf(zt[(lw * 8 + j) * 33 + co]);
      ssum += e;
      pk[j] = f2bf(e);
    }
    *(V16*)(out + (int64_t)co * 4096 + l0 + lw * 8) = *(V16*)&pk[0];
    __syncthreads();
  }
  rsum[t] = ssum;
  __syncthreads();
  if ((t & 7) == 0) {
    float S = 0.f;
#pragma unroll
    for (int k = 0; k < 8; ++k) S += rsum[t + k];
    partS[((int64_t)(b * 2 + sel) * 256 + cg * 32 + co) * 8 + ls] = S;
  }
}

__global__ void k_statsB(const float* __restrict__ part, float* __restrict__ inv) {
  int idx = blockIdx.x * 256 + threadIdx.x;   // 4096 channels (b*sel*c)
  float S = 0.f;
#pragma unroll
  for (int s = 0; s < 8; ++s) S += part[(int64_t)idx * 8 + s];
  inv[idx] = 1.0f / S;
}

// softmax over d of (sum split-K partials)*invSq[c]*invSk[d]*(1/16)
__global__ __launch_bounds__(256) void k_softmax_attn(
    const float* __restrict__ sc, const float* __restrict__ invS,
    u16* __restrict__ ma, int nsplit, int64_t splitOff) {
  int c = blockIdx.x, b = blockIdx.y;
  int64_t base = ((int64_t)b * 256 + c) * 256;
  int t = threadIdx.x;
  float z = 0.f;
  for (int s = 0; s < nsplit; ++s) z += sc[(int64_t)s * splitOff + base + t];
  float iq = invS[(int64_t)(b * 2 + 0) * 256 + c];
  float ik = invS[(int64_t)(b * 2 + 1) * 256 + t];
  z *= iq * ik * 0.0625f;
  __shared__ float red[256];
  red[t] = z; __syncthreads();
  for (int s = 128; s > 0; s >>= 1) { if (t < s) red[t] = fmaxf(red[t], red[t + s]); __syncthreads(); }
  float M = red[0]; __syncthreads();
  float p = __expf(z - M);
  red[t] = p; __syncthreads();
  for (int s = 128; s > 0; s >>= 1) { if (t < s) red[t] += red[t + s]; __syncthreads(); }
  ma[base + t] = f2bf(p / red[0]);
}

// ---------------------------------------------------------------------------
extern "C" void kernel_launch(void* const* d_in, const int* in_sizes, int n_in,
                              void* d_out, int out_size, void* d_ws, size_t ws_size,
                              hipStream_t stream) {
  (void)in_sizes; (void)n_in; (void)out_size; (void)ws_size;
  const float* x      = (const float*)d_in[0];
  const float* w_qkv  = (const float*)d_in[1];
  const float* w_mod  = (const float*)d_in[2];
  const float* w_res  = (const float*)d_in[3];
  const float* w_gate = (const float*)d_in[4];
  float* out = (float*)d_out;

  char* p = (char*)d_ws;
  auto take = [&](size_t n) { void* r = (void*)p; p += (n + 255) & ~(size_t)255; return r; };
  u16*    zpage  = (u16*)take(256);        // zero page for masked conv taps
  u16*    qkvT   = (u16*)take(50331648);   // [b][l][768] bf16 (q|k|v)
  u16*    modT   = (u16*)take(33554432);   // [b][l][512] bf16 (qm|km)
  u16*    ycatT  = (u16*)take(33554432);   // [b][l][512] bf16 (y|x)
  u16*    mq     = (u16*)take(16777216);   // [b][c][l] bf16 (unnormalized e)
  u16*    mk     = (u16*)take(16777216);   // [b][d][l] bf16 (contiguous after mq)
  float*  scores = (float*)take(16777216); // [8 splits][b][c][d] f32
  u16*    mattn  = (u16*)take(1048576);    // [b][c][d] bf16
  float*  yb     = (float*)take(33554432); // [b][c][l] f32
  float*  partS  = (float*)take(131072);   // [b*sel*c][8 lsplit] S partials
  float*  invS   = (float*)take(16384);    // [b*sel*c] 1/S
  u16*    Wa     = (u16*)take(3538944);    // 768 x 2304
  u16*    Wb     = (u16*)take(786432);     // 512 x 768
  u16*    Wg     = (u16*)take(262144);     // 256 x 512
  u16*    Wr     = (u16*)take(131072);     // 256 x 256
  float* resb = (float*)mq;                // alias: mq/mk dead after scores GEMM

  k_zero4<<<1, 64, 0, stream>>>((uint32_t*)zpage);
  k_conv_wqkv<<<6912, 256, 0, stream>>>(w_qkv, Wa);
  k_conv_wmod<<<1536, 256, 0, stream>>>(w_mod, Wb);
  k_convert<<<512, 256, 0, stream>>>(w_gate, Wg, 131072);
  k_convert<<<256, 256, 0, stream>>>(w_res, Wr, 65536);
  k_xT<<<dim3(64, 4, 8), 256, 0, stream>>>(x, ycatT);

  // qkv = conv2d(x, w_qkv): M=768 N=4096 K=9*256 -> qkvT bf16 (r9 overlap)
  gemmOv_bf16<2><<<384, 512, 0, stream>>>(
      Wa, ycatT + 256, qkvT,
      2304, 512, (int64_t)4096 * 512,
      768, (int64_t)4096 * 768, 3, zpage);

  // mod = conv1d(v, w_mod): M=512 N=4096 K=3*256 -> modT bf16 (r9 overlap)
  gemmOv_bf16<1><<<256, 512, 0, stream>>>(
      Wb, qkvT + 512, modT,
      768, 768, (int64_t)4096 * 768,
      512, (int64_t)4096 * 512, 2, zpage);

  // e_q/e_k = exp(-relu(q*qm)) unnormalized + per-channel sum partials
  k_mod_exp<<<dim3(8, 8, 16), 256, 0, stream>>>(qkvT, modT, mq, mk, partS);
  k_statsB<<<16, 256, 0, stream>>>(partS, invS);

  // scores'[c][d] = sum_l e_q[c,l]*e_k[d,l]: M=256 N=256 K=4096, split-K x8
  gemm_bf16<0, true, false><<<dim3(2, 2, 64), 256, 0, stream>>>(
      mq, mk, scores, nullptr,
      512, 4096, (int64_t)256 * 4096,
      4096, (int64_t)256 * 4096,
      256, (int64_t)256 * 256,
      0, 0,
      8, 512, (int64_t)8 * 256 * 256, zpage, nullptr, nullptr);

  k_softmax_attn<<<dim3(256, 8), 256, 0, stream>>>(
      scores, invS, mattn, 8, (int64_t)8 * 256 * 256);

  // y = m_attn @ v: M=256 N=4096 K=256 -> yb f32 + ycatT[:,0:256] bf16
  gemm_bf16<0, true, true><<<dim3(32, 2, 8), 256, 0, stream>>>(
      mattn, qkvT + 512, yb, ycatT,
      256, 256, (int64_t)256 * 256,
      768, (int64_t)4096 * 768,
      4096, (int64_t)256 * 4096,
      512, (int64_t)4096 * 512,
      1, 0, 0, zpage, nullptr, nullptr);

  // res = w_res @ x: M=256 N=4096 K=256 -> resb f32 (aliases dead mq/mk)
  gemm_bf16<0, true, false><<<dim3(32, 2, 8), 256, 0, stream>>>(
      Wr, ycatT + 256, resb, nullptr,
      256, 256, 0,
      512, (int64_t)4096 * 512,
      4096, (int64_t)256 * 4096,
      0, 0,
      1, 0, 0, zpage, nullptr, nullptr);

  // gate GEMM + FUSED final blend: gpre = w_gate @ [y;x], then
  // out = sigmoid(gpre)*res + (1-sigmoid(gpre))*y  (k_final eliminated)
  gemm_bf16<0, false, false, true><<<dim3(32, 2, 8), 256, 0, stream>>>(
      Wg, ycatT, out, nullptr,
      512, 512, 0,
      512, (int64_t)4096 * 512,
      4096, (int64_t)256 * 4096,
      0, 0,
      1, 0, 0, zpage, resb, yb);
}

// Round 12
// 291.545 us; speedup vs baseline: 1.1631x; 1.0414x over previous
//
#include <hip/hip_runtime.h>
#include <cstdint>

typedef unsigned short u16;
using bf16x8 = __attribute__((ext_vector_type(8))) short;   // 8 bf16 = 4 VGPR
using f32x4  = __attribute__((ext_vector_type(4))) float;   // MFMA acc

struct alignas(16) V16 { uint32_t a, b, c, d; };            // 16B chunk
struct alignas(8)  U16x4 { u16 a, b, c, d; };
struct alignas(16) F4 { float x, y, z, w; };

__device__ __forceinline__ u16 f2bf(float f) {              // RNE f32->bf16
  uint32_t u = __float_as_uint(f);
  u += 0x7fffu + ((u >> 16) & 1u);
  return (u16)(u >> 16);
}
__device__ __forceinline__ float bf2f(u16 h) {
  return __uint_as_float(((uint32_t)h) << 16);
}

// async global->LDS, 16B per lane; dest = wave-uniform base + lane*16 (linear)
#define GLOAD16(g, l) __builtin_amdgcn_global_load_lds(                         \
    (const __attribute__((address_space(1))) uint32_t*)(g),                     \
    (__attribute__((address_space(3))) uint32_t*)(l), 16, 0, 0)

// ===========================================================================
// Overlap-pipelined conv-GEMM (r9 structure, BM parameterized via MF):
// BM = MF*32 (MF=8 -> 256, MF=6 -> 192), BN=256, BK=64 slab, 8 waves
// (2M x 4N), per-wave (MF*16) x 64 (acc[MF][4]).
//   Out[b][m][n] = sum_t sum_k A[m][t*256+k] * Bact[b][n+off(t)][k]
// NO intra-slab fences -> compiler interleaves ds_read<->MFMA with counted
// lgkmcnt. LDS ring-2 dbuf; boundary = vmcnt(0)+barrier per slab.
// Swizzle: 128-B rows, chunk ^= (row&7) (0-conflict, r4/r6/r8/r9), applied
// on global SOURCE + ds_read side; gload_lds dest linear (rule #21).
// MF=6 exists to make conv2d's grid EXACT: M=768 -> 4 mtiles -> 512 blocks
// = 2 full rounds of 256 CUs (r9's 384 blocks = 1.5 rounds, 75% efficiency).
// ===========================================================================
template<int MODE, int MF>
__global__ __launch_bounds__(512, 2) void gemmOv_bf16(
    const u16* __restrict__ A, const u16* __restrict__ B, u16* __restrict__ otr,
    int sA, int sB, int64_t bBatch, int trStride, int64_t trBatch, int MT,
    const u16* __restrict__ zpage)
{
  constexpr int NS = (MODE == 2) ? 36 : 12;    // BK=64 slabs: NTAPS*(256/64)
  constexpr int ASL = MF * 2048;               // A slab u16 (BM*64)
  constexpr int SLAB = ASL + 16384;            // + B slab (256*64)
  __shared__ __align__(16) u16 lds[2 * SLAB];  // 112 KiB (MF=6) / 128 (MF=8)

  const int tid = threadIdx.x;
  const int q = gridDim.x >> 3;                // XCD-aware bijective swizzle
  const int flat = (blockIdx.x & 7) * q + (blockIdx.x >> 3);
  const int per_b = MT * 16;                   // 16 n-tiles of 256
  const int b = flat / per_b, rem = flat % per_b;
  const int ntile = rem / MT, mtile = rem % MT;
  const int m0 = mtile * (MF * 32), n0 = ntile * 256;
  const u16* Bb = B + (int64_t)b * bBatch;

  const int lane = tid & 63, wave = tid >> 6;
  const int wm = wave >> 2, wn = wave & 3;     // 2M x 4N waves
  const int lr = lane & 15, lc = lane >> 4;

  // staging: load (wave, j) fills 8 rows, contiguous 1KB; lane l ->
  // row_local l>>3, chunk l&7; source chunk pre-swizzled (row&7 == (l>>3)&7
  // since all row bases are multiples of 8).
  const int lrow8 = lane >> 3;
  const int sch  = lane & 7;
  const int scs  = sch ^ (lrow8 & 7);
  const u16* aSrc[MF / 2];
  const u16* bSrc[4];
  int bRow[4];
#pragma unroll
  for (int j = 0; j < MF / 2; ++j)
    aSrc[j] = A + (int64_t)(m0 + wave * (MF * 4) + j * 8 + lrow8) * sA + scs * 8;
#pragma unroll
  for (int j = 0; j < 4; ++j) {
    bRow[j] = n0 + wave * 32 + j * 8 + lrow8;
    bSrc[j] = Bb + (int64_t)bRow[j] * sB + scs * 8;
  }

  auto stageA = [&](int s) {                   // MF/2 loads/thread
    const int kOff = (s >> 2) * 256 + ((s & 3) << 6);
    u16* dst = lds + (s & 1) * SLAB + wave * (MF / 2) * 512;
#pragma unroll
    for (int j = 0; j < MF / 2; ++j)
      GLOAD16(aSrc[j] + kOff, dst + j * 512);
  };
  auto stageB = [&](int s) {                   // 4 loads/thread (tap-masked)
    const int tap = s >> 2, kc = (s & 3) << 6;
    int off, dh = 0, dw = 0;
    if constexpr (MODE == 2) { dh = tap / 3 - 1; dw = tap % 3 - 1; off = dh * 64 + dw; }
    else                     { off = tap - 1; }
    u16* dst = lds + (s & 1) * SLAB + ASL + wave * 2048;
#pragma unroll
    for (int j = 0; j < 4; ++j) {
      bool ok;
      if constexpr (MODE == 2) {
        int hh = (bRow[j] >> 6) + dh, ww = (bRow[j] & 63) + dw;
        ok = ((unsigned)hh < 64u) && ((unsigned)ww < 64u);
      } else {
        ok = ((unsigned)(bRow[j] + off) < 4096u);
      }
      const u16* src = ok ? (bSrc[j] + (int64_t)off * sB + kc) : zpage;
      GLOAD16(src, dst + j * 512);
    }
  };

  f32x4 acc[MF][4];
#pragma unroll
  for (int i = 0; i < MF; ++i)
#pragma unroll
    for (int j = 0; j < 4; ++j) acc[i][j] = f32x4{0.f, 0.f, 0.f, 0.f};

  stageA(0); stageB(0);
  asm volatile("s_waitcnt vmcnt(0)" ::: "memory");
  __builtin_amdgcn_s_barrier();
  __builtin_amdgcn_sched_barrier(0);

  for (int s = 0; s < NS; ++s) {
    const u16* As = lds + (s & 1) * SLAB;
    const u16* Bs = As + ASL;
    const bool pf = (s + 1 < NS);
    bf16x8 bfr[4], af[MF];

    // ---- k-half 0: reads + stage A(s+1) + MF*4 MFMA (compiler-interleaved)
#pragma unroll
    for (int nf = 0; nf < 4; ++nf) {
      int row = wn * 64 + nf * 16 + lr;
      bfr[nf] = *(const bf16x8*)&Bs[row * 64 + ((lc ^ (row & 7)) * 8)];
    }
#pragma unroll
    for (int mf = 0; mf < MF; ++mf) {
      int row = wm * (MF * 16) + mf * 16 + lr;
      af[mf] = *(const bf16x8*)&As[row * 64 + ((lc ^ (row & 7)) * 8)];
    }
    if (pf) stageA(s + 1);
#pragma unroll
    for (int mf = 0; mf < MF; ++mf)
#pragma unroll
      for (int nf = 0; nf < 4; ++nf)
        acc[mf][nf] = __builtin_amdgcn_mfma_f32_16x16x32_bf16(af[mf], bfr[nf], acc[mf][nf], 0, 0, 0);

    // ---- k-half 1: reads + stage B(s+1) + MF*4 MFMA
#pragma unroll
    for (int nf = 0; nf < 4; ++nf) {
      int row = wn * 64 + nf * 16 + lr;
      bfr[nf] = *(const bf16x8*)&Bs[row * 64 + (((4 + lc) ^ (row & 7)) * 8)];
    }
#pragma unroll
    for (int mf = 0; mf < MF; ++mf) {
      int row = wm * (MF * 16) + mf * 16 + lr;
      af[mf] = *(const bf16x8*)&As[row * 64 + (((4 + lc) ^ (row & 7)) * 8)];
    }
    if (pf) stageB(s + 1);
#pragma unroll
    for (int mf = 0; mf < MF; ++mf)
#pragma unroll
      for (int nf = 0; nf < 4; ++nf)
        acc[mf][nf] = __builtin_amdgcn_mfma_f32_16x16x32_bf16(af[mf], bfr[nf], acc[mf][nf], 0, 0, 0);

    if (pf) {
      asm volatile("s_waitcnt vmcnt(0)" ::: "memory");
      __builtin_amdgcn_s_barrier();
      __builtin_amdgcn_sched_barrier(0);
    }
  }

  // epilogue: C/D layout col=lane&15, row=(lane>>4)*4+reg; write transposed
#pragma unroll
  for (int mf = 0; mf < MF; ++mf)
#pragma unroll
    for (int nf = 0; nf < 4; ++nf) {
      f32x4 v = acc[mf][nf];
      int m = m0 + wm * (MF * 16) + mf * 16 + lc * 4;
      int n = n0 + wn * 64 + nf * 16 + lr;
      U16x4 pk{f2bf(v[0]), f2bf(v[1]), f2bf(v[2]), f2bf(v[3])};
      *(U16x4*)(otr + trBatch * b + (int64_t)n * trStride + m) = pk;
    }
}

// ---------------------------------------------------------------------------
// 128x128 GEMM (dense stages: scores, y, res, gate[+fused sigmoid blend])
// ---------------------------------------------------------------------------
template<int MODE, bool WR_RM, bool WR_TR, bool WR_FOUT = false>
__global__ __launch_bounds__(256) void gemm_bf16(
    const u16* __restrict__ A, const u16* __restrict__ B,
    float* __restrict__ orm, u16* __restrict__ otr,
    int Kc, int sA, int64_t aBatch,
    int sB, int64_t bBatch,
    int rmStride, int64_t rmBatch,
    int trStride, int64_t trBatch,
    int nsplit, int kStep, int64_t splitOut,
    const u16* __restrict__ zpage,
    const float* __restrict__ frs, const float* __restrict__ fyy)
{
  constexpr int NTAPS = (MODE == 2) ? 9 : (MODE == 1 ? 3 : 1);
  __shared__ __align__(16) u16 As[128 * 32];
  __shared__ __align__(16) u16 Bs[128 * 32];

  const int tid = threadIdx.x;
  int b = blockIdx.z, split = 0;
  if (nsplit > 1) { split = b % nsplit; b /= nsplit; }
  const int m0  = blockIdx.y * 128;
  const int n0  = blockIdx.x * 128;
  const int lane = tid & 63, wave = tid >> 6;
  const int wm = wave >> 1, wn = wave & 1;
  const int lr = lane & 15, lc = lane >> 4;

  f32x4 acc[4][4];
#pragma unroll
  for (int i = 0; i < 4; ++i)
#pragma unroll
    for (int j = 0; j < 4; ++j) acc[i][j] = f32x4{0.f, 0.f, 0.f, 0.f};

  const u16* Ab = A + (int64_t)b * aBatch + split * kStep;
  const u16* Bb = B + (int64_t)b * bBatch + split * kStep;

  const int srow = tid >> 2;
  const int sc   = tid & 3;
  const int scs  = sc ^ (srow & 3);

  for (int t = 0; t < NTAPS; ++t) {
    int dh = 0, dw = 0, off = 0;
    if constexpr (MODE == 2) { dh = t / 3 - 1; dw = t % 3 - 1; off = dh * 64 + dw; }
    if constexpr (MODE == 1) { off = t - 1; }

    for (int kc = 0; kc < Kc; kc += 32) {
      const int kA = t * Kc + kc;
#pragma unroll
      for (int it = 0; it < 2; ++it) {
        int row = srow + it * 64;
        GLOAD16(Ab + (int64_t)(m0 + row) * sA + kA + scs * 8,
                &As[wave * 512 + it * 2048]);
      }
#pragma unroll
      for (int it = 0; it < 2; ++it) {
        int row = srow + it * 64;
        int l = n0 + row;
        int gl = l + off;
        bool ok = true;
        if constexpr (MODE == 2) {
          int hh = (l >> 6) + dh, ww = (l & 63) + dw;
          ok = ((unsigned)hh < 64u) && ((unsigned)ww < 64u);
        }
        if constexpr (MODE == 1) { ok = ((unsigned)gl < 4096u); }
        const u16* src = ok ? (Bb + (int64_t)gl * sB + kc + scs * 8) : zpage;
        GLOAD16(src, &Bs[wave * 512 + it * 2048]);
      }
      __syncthreads();

      bf16x8 af[4], bfr[4];
#pragma unroll
      for (int mf = 0; mf < 4; ++mf) {
        int row = wm * 64 + mf * 16 + lr;
        int cs = lc ^ (row & 3);
        af[mf] = *(const bf16x8*)&As[row * 32 + cs * 8];
      }
#pragma unroll
      for (int nf = 0; nf < 4; ++nf) {
        int row = wn * 64 + nf * 16 + lr;
        int cs = lc ^ (row & 3);
        bfr[nf] = *(const bf16x8*)&Bs[row * 32 + cs * 8];
      }
#pragma unroll
      for (int mf = 0; mf < 4; ++mf)
#pragma unroll
        for (int nf = 0; nf < 4; ++nf)
          acc[mf][nf] = __builtin_amdgcn_mfma_f32_16x16x32_bf16(af[mf], bfr[nf], acc[mf][nf], 0, 0, 0);
      __syncthreads();
    }
  }

#pragma unroll
  for (int mf = 0; mf < 4; ++mf) {
#pragma unroll
    for (int nf = 0; nf < 4; ++nf) {
      f32x4 v = acc[mf][nf];
      int m = m0 + wm * 64 + mf * 16 + lc * 4;
      int n = n0 + wn * 64 + nf * 16 + lr;
      if constexpr (WR_FOUT) {
        int64_t off = rmBatch * b + (int64_t)m * rmStride + n;
        float* p = orm + off;
        const float* pr = frs + off;
        const float* py = fyy + off;
#pragma unroll
        for (int r = 0; r < 4; ++r) {
          float g = 1.f / (1.f + __expf(-v[r]));
          p[(int64_t)r * rmStride] =
              g * pr[(int64_t)r * rmStride] + (1.f - g) * py[(int64_t)r * rmStride];
        }
      }
      if constexpr (WR_RM) {
        float* p = orm + splitOut * split + rmBatch * b + (int64_t)m * rmStride + n;
#pragma unroll
        for (int r = 0; r < 4; ++r) p[(int64_t)r * rmStride] = v[r];
      }
      if constexpr (WR_TR) {
        U16x4 pk{f2bf(v[0]), f2bf(v[1]), f2bf(v[2]), f2bf(v[3])};
        *(U16x4*)(otr + trBatch * b + (int64_t)n * trStride + m) = pk;
      }
    }
  }
}

// ---------------------------------------------------------------------------
// weight converts + zero page
// ---------------------------------------------------------------------------
__global__ void k_zero4(uint32_t* __restrict__ p) { p[threadIdx.x] = 0u; }

__global__ void k_conv_wqkv(const float* __restrict__ w, u16* __restrict__ o) {
  int idx = blockIdx.x * 256 + threadIdx.x;           // 768*2304
  if (idx >= 768 * 2304) return;
  int oc = idx / 2304, r = idx % 2304;
  int t = r >> 8, ic = r & 255;
  int kh = t / 3, kw = t % 3;
  o[idx] = f2bf(w[((oc * 256 + ic) * 3 + kh) * 3 + kw]);
}
__global__ void k_conv_wmod(const float* __restrict__ w, u16* __restrict__ o) {
  int idx = blockIdx.x * 256 + threadIdx.x;           // 512*768
  if (idx >= 512 * 768) return;
  int oc = idx / 768, r = idx % 768;
  int t = r >> 8, ic = r & 255;
  o[idx] = f2bf(w[(oc * 256 + ic) * 3 + t]);
}
__global__ void k_convert(const float* __restrict__ in, u16* __restrict__ o, int n) {
  int idx = blockIdx.x * 256 + threadIdx.x;
  if (idx < n) o[idx] = f2bf(in[idx]);
}

// ---------------------------------------------------------------------------
// x (B,256,4096) f32 -> ycatT[b][l][256+c] bf16 (x part of concat buffer)
// ---------------------------------------------------------------------------
__global__ __launch_bounds__(256) void k_xT(const float* __restrict__ x, u16* __restrict__ ycat) {
  __shared__ float tile[64 * 68];
  int b = blockIdx.z, c0 = blockIdx.y * 64, l0 = blockIdx.x * 64;
  int t = threadIdx.x;
  int cc = t >> 2, part = t & 3;
  const float* xp = x + ((int64_t)(b * 256 + c0 + cc)) * 4096 + l0 + part * 16;
#pragma unroll
  for (int j = 0; j < 4; ++j) {
    F4 v = *(const F4*)(xp + j * 4);
    float* tp = &tile[cc * 68 + part * 16 + j * 4];
    tp[0] = v.x; tp[1] = v.y; tp[2] = v.z; tp[3] = v.w;
  }
  __syncthreads();
  int l = t >> 2;
  u16* op = ycat + ((int64_t)b * 4096 + l0 + l) * 512 + 256 + c0 + part * 16;
  __align__(16) u16 tmp[16];
#pragma unroll
  for (int j = 0; j < 16; ++j) tmp[j] = f2bf(tile[(part * 16 + j) * 68 + l]);
  *(V16*)(op) = *(V16*)&tmp[0];
  *(V16*)(op + 8) = *(V16*)&tmp[8];
}

// ---------------------------------------------------------------------------
// Mod softmax, max-free + deferred normalization (r11):
//   z = -relu(q*qm) <= 0 -> exp(z) in (0,1], no max pass needed.
//   Write unnormalized e = exp(z) bf16; per-channel sums S -> invS applied
//   as scalars inside k_softmax_attn.
// ---------------------------------------------------------------------------
__global__ __launch_bounds__(256) void k_mod_exp(
    const u16* __restrict__ qkvT, const u16* __restrict__ modT,
    u16* __restrict__ mq, u16* __restrict__ mk, float* __restrict__ partS)
{
  int cg = blockIdx.x, ls = blockIdx.y;
  int b = blockIdx.z >> 1, sel = blockIdx.z & 1;
  int coff = cg * 32 + (sel ? 256 : 0);
  const u16* qp = qkvT + (int64_t)b * 4096 * 768 + coff;
  const u16* mp = modT + (int64_t)b * 4096 * 512 + coff;
  u16* out = (sel ? mk : mq) + ((int64_t)b * 256 + cg * 32) * 4096;

  __shared__ float zt[64 * 33];
  __shared__ float rsum[256];
  int t = threadIdx.x;
  int lrow = t >> 2, part4 = t & 3;
  int co = t >> 3, lw = t & 7;
  float ssum = 0.f;
  int lbase = ls * 512;
  for (int l0 = lbase; l0 < lbase + 512; l0 += 64) {
    V16 qv = *(const V16*)(qp + (int64_t)(l0 + lrow) * 768 + part4 * 8);
    V16 mv = *(const V16*)(mp + (int64_t)(l0 + lrow) * 512 + part4 * 8);
    const u16* qu = (const u16*)&qv;
    const u16* mu = (const u16*)&mv;
#pragma unroll
    for (int j = 0; j < 8; ++j) {
      float z = bf2f(qu[j]) * bf2f(mu[j]);
      zt[lrow * 33 + part4 * 8 + j] = z > 0.f ? -z : 0.f;
    }
    __syncthreads();
    __align__(16) u16 pk[8];
#pragma unroll
    for (int j = 0; j < 8; ++j) {
      float e = __expf(zt[(lw * 8 + j) * 33 + co]);
      ssum += e;
      pk[j] = f2bf(e);
    }
    *(V16*)(out + (int64_t)co * 4096 + l0 + lw * 8) = *(V16*)&pk[0];
    __syncthreads();
  }
  rsum[t] = ssum;
  __syncthreads();
  if ((t & 7) == 0) {
    float S = 0.f;
#pragma unroll
    for (int k = 0; k < 8; ++k) S += rsum[t + k];
    partS[((int64_t)(b * 2 + sel) * 256 + cg * 32 + co) * 8 + ls] = S;
  }
}

__global__ void k_statsB(const float* __restrict__ part, float* __restrict__ inv) {
  int idx = blockIdx.x * 256 + threadIdx.x;   // 4096 channels (b*sel*c)
  float S = 0.f;
#pragma unroll
  for (int s = 0; s < 8; ++s) S += part[(int64_t)idx * 8 + s];
  inv[idx] = 1.0f / S;
}

// softmax over d of (sum split-K partials)*invSq[c]*invSk[d]*(1/16)
__global__ __launch_bounds__(256) void k_softmax_attn(
    const float* __restrict__ sc, const float* __restrict__ invS,
    u16* __restrict__ ma, int nsplit, int64_t splitOff) {
  int c = blockIdx.x, b = blockIdx.y;
  int64_t base = ((int64_t)b * 256 + c) * 256;
  int t = threadIdx.x;
  float z = 0.f;
  for (int s = 0; s < nsplit; ++s) z += sc[(int64_t)s * splitOff + base + t];
  float iq = invS[(int64_t)(b * 2 + 0) * 256 + c];
  float ik = invS[(int64_t)(b * 2 + 1) * 256 + t];
  z *= iq * ik * 0.0625f;
  __shared__ float red[256];
  red[t] = z; __syncthreads();
  for (int s = 128; s > 0; s >>= 1) { if (t < s) red[t] = fmaxf(red[t], red[t + s]); __syncthreads(); }
  float M = red[0]; __syncthreads();
  float p = __expf(z - M);
  red[t] = p; __syncthreads();
  for (int s = 128; s > 0; s >>= 1) { if (t < s) red[t] += red[t + s]; __syncthreads(); }
  ma[base + t] = f2bf(p / red[0]);
}

// ---------------------------------------------------------------------------
extern "C" void kernel_launch(void* const* d_in, const int* in_sizes, int n_in,
                              void* d_out, int out_size, void* d_ws, size_t ws_size,
                              hipStream_t stream) {
  (void)in_sizes; (void)n_in; (void)out_size; (void)ws_size;
  const float* x      = (const float*)d_in[0];
  const float* w_qkv  = (const float*)d_in[1];
  const float* w_mod  = (const float*)d_in[2];
  const float* w_res  = (const float*)d_in[3];
  const float* w_gate = (const float*)d_in[4];
  float* out = (float*)d_out;

  char* p = (char*)d_ws;
  auto take = [&](size_t n) { void* r = (void*)p; p += (n + 255) & ~(size_t)255; return r; };
  u16*    zpage  = (u16*)take(256);        // zero page for masked conv taps
  u16*    qkvT   = (u16*)take(50331648);   // [b][l][768] bf16 (q|k|v)
  u16*    modT   = (u16*)take(33554432);   // [b][l][512] bf16 (qm|km)
  u16*    ycatT  = (u16*)take(33554432);   // [b][l][512] bf16 (y|x)
  u16*    mq     = (u16*)take(16777216);   // [b][c][l] bf16 (unnormalized e)
  u16*    mk     = (u16*)take(16777216);   // [b][d][l] bf16 (contiguous after mq)
  float*  scores = (float*)take(16777216); // [8 splits][b][c][d] f32
  u16*    mattn  = (u16*)take(1048576);    // [b][c][d] bf16
  float*  yb     = (float*)take(33554432); // [b][c][l] f32
  float*  partS  = (float*)take(131072);   // [b*sel*c][8 lsplit] S partials
  float*  invS   = (float*)take(16384);    // [b*sel*c] 1/S
  u16*    Wa     = (u16*)take(3538944);    // 768 x 2304
  u16*    Wb     = (u16*)take(786432);     // 512 x 768
  u16*    Wg     = (u16*)take(262144);     // 256 x 512
  u16*    Wr     = (u16*)take(131072);     // 256 x 256
  float* resb = (float*)mq;                // alias: mq/mk dead after scores GEMM

  k_zero4<<<1, 64, 0, stream>>>((uint32_t*)zpage);
  k_conv_wqkv<<<6912, 256, 0, stream>>>(w_qkv, Wa);
  k_conv_wmod<<<1536, 256, 0, stream>>>(w_mod, Wb);
  k_convert<<<512, 256, 0, stream>>>(w_gate, Wg, 131072);
  k_convert<<<256, 256, 0, stream>>>(w_res, Wr, 65536);
  k_xT<<<dim3(64, 4, 8), 256, 0, stream>>>(x, ycatT);

  // qkv = conv2d(x, w_qkv): M=768 N=4096 K=9*256 -> qkvT bf16
  // BM=192 (MF=6): 4 mtiles x 16 ntiles x 8 = 512 blocks = 2 EXACT rounds
  gemmOv_bf16<2, 6><<<512, 512, 0, stream>>>(
      Wa, ycatT + 256, qkvT,
      2304, 512, (int64_t)4096 * 512,
      768, (int64_t)4096 * 768, 4, zpage);

  // mod = conv1d(v, w_mod): M=512 N=4096 K=3*256 -> modT bf16 (BM=256, exact)
  gemmOv_bf16<1, 8><<<256, 512, 0, stream>>>(
      Wb, qkvT + 512, modT,
      768, 768, (int64_t)4096 * 768,
      512, (int64_t)4096 * 512, 2, zpage);

  // e_q/e_k = exp(-relu(q*qm)) unnormalized + per-channel sum partials
  k_mod_exp<<<dim3(8, 8, 16), 256, 0, stream>>>(qkvT, modT, mq, mk, partS);
  k_statsB<<<16, 256, 0, stream>>>(partS, invS);

  // scores'[c][d] = sum_l e_q[c,l]*e_k[d,l]: M=256 N=256 K=4096, split-K x8
  gemm_bf16<0, true, false><<<dim3(2, 2, 64), 256, 0, stream>>>(
      mq, mk, scores, nullptr,
      512, 4096, (int64_t)256 * 4096,
      4096, (int64_t)256 * 4096,
      256, (int64_t)256 * 256,
      0, 0,
      8, 512, (int64_t)8 * 256 * 256, zpage, nullptr, nullptr);

  k_softmax_attn<<<dim3(256, 8), 256, 0, stream>>>(
      scores, invS, mattn, 8, (int64_t)8 * 256 * 256);

  // y = m_attn @ v: M=256 N=4096 K=256 -> yb f32 + ycatT[:,0:256] bf16
  gemm_bf16<0, true, true><<<dim3(32, 2, 8), 256, 0, stream>>>(
      mattn, qkvT + 512, yb, ycatT,
      256, 256, (int64_t)256 * 256,
      768, (int64_t)4096 * 768,
      4096, (int64_t)256 * 4096,
      512, (int64_t)4096 * 512,
      1, 0, 0, zpage, nullptr, nullptr);

  // res = w_res @ x: M=256 N=4096 K=256 -> resb f32 (aliases dead mq/mk)
  gemm_bf16<0, true, false><<<dim3(32, 2, 8), 256, 0, stream>>>(
      Wr, ycatT + 256, resb, nullptr,
      256, 256, 0,
      512, (int64_t)4096 * 512,
      4096, (int64_t)256 * 4096,
      0, 0,
      1, 0, 0, zpage, nullptr, nullptr);

  // gate GEMM + FUSED final blend: out = sig(gpre)*res + (1-sig(gpre))*y
  gemm_bf16<0, false, false, true><<<dim3(32, 2, 8), 256, 0, stream>>>(
      Wg, ycatT, out, nullptr,
      512, 512, 0,
      512, (int64_t)4096 * 512,
      4096, (int64_t)256 * 4096,
      0, 0,
      1, 0, 0, zpage, resb, yb);
}

// Round 13
// 260.847 us; speedup vs baseline: 1.3000x; 1.1177x over previous
//
#include <hip/hip_runtime.h>
#include <cstdint>

typedef unsigned short u16;
using bf16x8 = __attribute__((ext_vector_type(8))) short;   // 8 bf16 = 4 VGPR
using f32x4  = __attribute__((ext_vector_type(4))) float;   // MFMA acc

struct alignas(16) V16 { uint32_t a, b, c, d; };            // 16B chunk
struct alignas(8)  U16x4 { u16 a, b, c, d; };
struct alignas(16) F4 { float x, y, z, w; };

__device__ __forceinline__ u16 f2bf(float f) {              // RNE f32->bf16
  uint32_t u = __float_as_uint(f);
  u += 0x7fffu + ((u >> 16) & 1u);
  return (u16)(u >> 16);
}
__device__ __forceinline__ float bf2f(u16 h) {
  return __uint_as_float(((uint32_t)h) << 16);
}

// async global->LDS, 16B per lane; dest = wave-uniform base + lane*16 (linear)
#define GLOAD16(g, l) __builtin_amdgcn_global_load_lds(                         \
    (const __attribute__((address_space(1))) uint32_t*)(g),                     \
    (__attribute__((address_space(3))) uint32_t*)(l), 16, 0, 0)

// ===========================================================================
// Overlap-pipelined conv-GEMM (r9 structure, BM = MF*32, BN=256, BK=64 slab,
// 8 waves 2M x 4N, per-wave (MF*16)x64, acc[MF][4]).
//   Out[b][m][n] = sum_t sum_k A[m][t*256+k] * Bact[b][n+off(t)][k]
// NO intra-slab fences -> compiler interleaves ds_read<->MFMA with counted
// lgkmcnt. LDS ring-2 dbuf; boundary = vmcnt(0)+barrier per slab.
// Swizzle: 128-B rows, chunk ^= (row&7) (0-conflict), applied on global
// SOURCE + ds_read side; gload_lds dest linear (rule #21).
// FUSE=1 (conv1d only): epilogue computes e = exp(-relu(q*mod)) directly
// (q/k partner channel in qkvT == mod channel m, since q=0:256, k=256:512),
// writes e bf16 to interleaved eT[b][512][4096], and emits deterministic
// per-(channel, ntile*4+wn) partial sums via __shfl_xor lr-reduction ->
// partS[b*512+ch][64]. Eliminates modT buffer + the whole mod_exp pass.
// ===========================================================================
template<int MODE, int MF, int FUSE = 0>
__global__ __launch_bounds__(512, 2) void gemmOv_bf16(
    const u16* __restrict__ A, const u16* __restrict__ B, u16* __restrict__ otr,
    int sA, int sB, int64_t bBatch, int trStride, int64_t trBatch, int MT,
    const u16* __restrict__ zpage,
    const u16* __restrict__ fq = nullptr, u16* __restrict__ eOut = nullptr,
    float* __restrict__ partS = nullptr)
{
  constexpr int NS = (MODE == 2) ? 36 : 12;    // BK=64 slabs: NTAPS*(256/64)
  constexpr int ASL = MF * 2048;               // A slab u16 (BM*64)
  constexpr int SLAB = ASL + 16384;            // + B slab (256*64)
  __shared__ __align__(16) u16 lds[2 * SLAB];

  const int tid = threadIdx.x;
  const int q = gridDim.x >> 3;                // XCD-aware bijective swizzle
  const int flat = (blockIdx.x & 7) * q + (blockIdx.x >> 3);
  const int per_b = MT * 16;                   // 16 n-tiles of 256
  const int b = flat / per_b, rem = flat % per_b;
  const int ntile = rem / MT, mtile = rem % MT;
  const int m0 = mtile * (MF * 32), n0 = ntile * 256;
  const u16* Bb = B + (int64_t)b * bBatch;

  const int lane = tid & 63, wave = tid >> 6;
  const int wm = wave >> 2, wn = wave & 3;     // 2M x 4N waves
  const int lr = lane & 15, lc = lane >> 4;

  const int lrow8 = lane >> 3;
  const int sch  = lane & 7;
  const int scs  = sch ^ (lrow8 & 7);
  const u16* aSrc[MF / 2];
  const u16* bSrc[4];
  int bRow[4];
#pragma unroll
  for (int j = 0; j < MF / 2; ++j)
    aSrc[j] = A + (int64_t)(m0 + wave * (MF * 4) + j * 8 + lrow8) * sA + scs * 8;
#pragma unroll
  for (int j = 0; j < 4; ++j) {
    bRow[j] = n0 + wave * 32 + j * 8 + lrow8;
    bSrc[j] = Bb + (int64_t)bRow[j] * sB + scs * 8;
  }

  auto stageA = [&](int s) {                   // MF/2 loads/thread
    const int kOff = (s >> 2) * 256 + ((s & 3) << 6);
    u16* dst = lds + (s & 1) * SLAB + wave * (MF / 2) * 512;
#pragma unroll
    for (int j = 0; j < MF / 2; ++j)
      GLOAD16(aSrc[j] + kOff, dst + j * 512);
  };
  auto stageB = [&](int s) {                   // 4 loads/thread (tap-masked)
    const int tap = s >> 2, kc = (s & 3) << 6;
    int off, dh = 0, dw = 0;
    if constexpr (MODE == 2) { dh = tap / 3 - 1; dw = tap % 3 - 1; off = dh * 64 + dw; }
    else                     { off = tap - 1; }
    u16* dst = lds + (s & 1) * SLAB + ASL + wave * 2048;
#pragma unroll
    for (int j = 0; j < 4; ++j) {
      bool ok;
      if constexpr (MODE == 2) {
        int hh = (bRow[j] >> 6) + dh, ww = (bRow[j] & 63) + dw;
        ok = ((unsigned)hh < 64u) && ((unsigned)ww < 64u);
      } else {
        ok = ((unsigned)(bRow[j] + off) < 4096u);
      }
      const u16* src = ok ? (bSrc[j] + (int64_t)off * sB + kc) : zpage;
      GLOAD16(src, dst + j * 512);
    }
  };

  f32x4 acc[MF][4];
#pragma unroll
  for (int i = 0; i < MF; ++i)
#pragma unroll
    for (int j = 0; j < 4; ++j) acc[i][j] = f32x4{0.f, 0.f, 0.f, 0.f};

  stageA(0); stageB(0);
  asm volatile("s_waitcnt vmcnt(0)" ::: "memory");
  __builtin_amdgcn_s_barrier();
  __builtin_amdgcn_sched_barrier(0);

  for (int s = 0; s < NS; ++s) {
    const u16* As = lds + (s & 1) * SLAB;
    const u16* Bs = As + ASL;
    const bool pf = (s + 1 < NS);
    bf16x8 bfr[4], af[MF];

    // ---- k-half 0: reads + stage A(s+1) + MF*4 MFMA (compiler-interleaved)
#pragma unroll
    for (int nf = 0; nf < 4; ++nf) {
      int row = wn * 64 + nf * 16 + lr;
      bfr[nf] = *(const bf16x8*)&Bs[row * 64 + ((lc ^ (row & 7)) * 8)];
    }
#pragma unroll
    for (int mf = 0; mf < MF; ++mf) {
      int row = wm * (MF * 16) + mf * 16 + lr;
      af[mf] = *(const bf16x8*)&As[row * 64 + ((lc ^ (row & 7)) * 8)];
    }
    if (pf) stageA(s + 1);
#pragma unroll
    for (int mf = 0; mf < MF; ++mf)
#pragma unroll
      for (int nf = 0; nf < 4; ++nf)
        acc[mf][nf] = __builtin_amdgcn_mfma_f32_16x16x32_bf16(af[mf], bfr[nf], acc[mf][nf], 0, 0, 0);

    // ---- k-half 1: reads + stage B(s+1) + MF*4 MFMA
#pragma unroll
    for (int nf = 0; nf < 4; ++nf) {
      int row = wn * 64 + nf * 16 + lr;
      bfr[nf] = *(const bf16x8*)&Bs[row * 64 + (((4 + lc) ^ (row & 7)) * 8)];
    }
#pragma unroll
    for (int mf = 0; mf < MF; ++mf) {
      int row = wm * (MF * 16) + mf * 16 + lr;
      af[mf] = *(const bf16x8*)&As[row * 64 + (((4 + lc) ^ (row & 7)) * 8)];
    }
    if (pf) stageB(s + 1);
#pragma unroll
    for (int mf = 0; mf < MF; ++mf)
#pragma unroll
      for (int nf = 0; nf < 4; ++nf)
        acc[mf][nf] = __builtin_amdgcn_mfma_f32_16x16x32_bf16(af[mf], bfr[nf], acc[mf][nf], 0, 0, 0);

    if (pf) {
      asm volatile("s_waitcnt vmcnt(0)" ::: "memory");
      __builtin_amdgcn_s_barrier();
      __builtin_amdgcn_sched_barrier(0);
    }
  }

  if constexpr (FUSE) {
    // fused e = exp(-relu(q * mod)) epilogue + deterministic partial sums
    const u16* qk = fq + (int64_t)b * 4096 * 768;
    u16* eb = eOut + (int64_t)b * 512 * 4096;
    float* ps = partS + (int64_t)b * 512 * 64;
#pragma unroll
    for (int mf = 0; mf < MF; ++mf) {
      const int mbase = m0 + wm * (MF * 16) + mf * 16 + lc * 4;
      float sp[4] = {0.f, 0.f, 0.f, 0.f};
#pragma unroll
      for (int nf = 0; nf < 4; ++nf) {
        int n = n0 + wn * 64 + nf * 16 + lr;
        U16x4 qv = *(const U16x4*)(qk + (int64_t)n * 768 + mbase);
        const u16* qp = (const u16*)&qv;
        f32x4 v = acc[mf][nf];
#pragma unroll
        for (int r = 0; r < 4; ++r) {
          float z = bf2f(qp[r]) * v[r];
          float e = __expf(z > 0.f ? -z : 0.f);
          sp[r] += e;
          eb[(int64_t)(mbase + r) * 4096 + n] = f2bf(e);
        }
      }
#pragma unroll
      for (int r = 0; r < 4; ++r) {
        float sv = sp[r];
        sv += __shfl_xor(sv, 1);
        sv += __shfl_xor(sv, 2);
        sv += __shfl_xor(sv, 4);
        sv += __shfl_xor(sv, 8);
        if (lr == 0)
          ps[(int64_t)(mbase + r) * 64 + ntile * 4 + wn] = sv;
      }
    }
  } else {
    // epilogue: C/D layout col=lane&15, row=(lane>>4)*4+reg; write transposed
#pragma unroll
    for (int mf = 0; mf < MF; ++mf)
#pragma unroll
      for (int nf = 0; nf < 4; ++nf) {
        f32x4 v = acc[mf][nf];
        int m = m0 + wm * (MF * 16) + mf * 16 + lc * 4;
        int n = n0 + wn * 64 + nf * 16 + lr;
        U16x4 pk{f2bf(v[0]), f2bf(v[1]), f2bf(v[2]), f2bf(v[3])};
        *(U16x4*)(otr + trBatch * b + (int64_t)n * trStride + m) = pk;
      }
  }
}

// ---------------------------------------------------------------------------
// 128x128 GEMM (dense stages: scores, y, res, gate[+fused sigmoid blend])
// WR_FOUT: out = sig(gpre)*res(f32) + (1-sig(gpre))*y(bf16 from ycatT)
// ---------------------------------------------------------------------------
template<int MODE, bool WR_RM, bool WR_TR, bool WR_FOUT = false>
__global__ __launch_bounds__(256) void gemm_bf16(
    const u16* __restrict__ A, const u16* __restrict__ B,
    float* __restrict__ orm, u16* __restrict__ otr,
    int Kc, int sA, int64_t aBatch,
    int sB, int64_t bBatch,
    int rmStride, int64_t rmBatch,
    int trStride, int64_t trBatch,
    int nsplit, int kStep, int64_t splitOut,
    const u16* __restrict__ zpage,
    const float* __restrict__ frs, const u16* __restrict__ fyt)
{
  constexpr int NTAPS = (MODE == 2) ? 9 : (MODE == 1 ? 3 : 1);
  __shared__ __align__(16) u16 As[128 * 32];
  __shared__ __align__(16) u16 Bs[128 * 32];

  const int tid = threadIdx.x;
  int b = blockIdx.z, split = 0;
  if (nsplit > 1) { split = b % nsplit; b /= nsplit; }
  const int m0  = blockIdx.y * 128;
  const int n0  = blockIdx.x * 128;
  const int lane = tid & 63, wave = tid >> 6;
  const int wm = wave >> 1, wn = wave & 1;
  const int lr = lane & 15, lc = lane >> 4;

  f32x4 acc[4][4];
#pragma unroll
  for (int i = 0; i < 4; ++i)
#pragma unroll
    for (int j = 0; j < 4; ++j) acc[i][j] = f32x4{0.f, 0.f, 0.f, 0.f};

  const u16* Ab = A + (int64_t)b * aBatch + split * kStep;
  const u16* Bb = B + (int64_t)b * bBatch + split * kStep;

  const int srow = tid >> 2;
  const int sc   = tid & 3;
  const int scs  = sc ^ (srow & 3);

  for (int t = 0; t < NTAPS; ++t) {
    int dh = 0, dw = 0, off = 0;
    if constexpr (MODE == 2) { dh = t / 3 - 1; dw = t % 3 - 1; off = dh * 64 + dw; }
    if constexpr (MODE == 1) { off = t - 1; }

    for (int kc = 0; kc < Kc; kc += 32) {
      const int kA = t * Kc + kc;
#pragma unroll
      for (int it = 0; it < 2; ++it) {
        int row = srow + it * 64;
        GLOAD16(Ab + (int64_t)(m0 + row) * sA + kA + scs * 8,
                &As[wave * 512 + it * 2048]);
      }
#pragma unroll
      for (int it = 0; it < 2; ++it) {
        int row = srow + it * 64;
        int l = n0 + row;
        int gl = l + off;
        bool ok = true;
        if constexpr (MODE == 2) {
          int hh = (l >> 6) + dh, ww = (l & 63) + dw;
          ok = ((unsigned)hh < 64u) && ((unsigned)ww < 64u);
        }
        if constexpr (MODE == 1) { ok = ((unsigned)gl < 4096u); }
        const u16* src = ok ? (Bb + (int64_t)gl * sB + kc + scs * 8) : zpage;
        GLOAD16(src, &Bs[wave * 512 + it * 2048]);
      }
      __syncthreads();

      bf16x8 af[4], bfr[4];
#pragma unroll
      for (int mf = 0; mf < 4; ++mf) {
        int row = wm * 64 + mf * 16 + lr;
        int cs = lc ^ (row & 3);
        af[mf] = *(const bf16x8*)&As[row * 32 + cs * 8];
      }
#pragma unroll
      for (int nf = 0; nf < 4; ++nf) {
        int row = wn * 64 + nf * 16 + lr;
        int cs = lc ^ (row & 3);
        bfr[nf] = *(const bf16x8*)&Bs[row * 32 + cs * 8];
      }
#pragma unroll
      for (int mf = 0; mf < 4; ++mf)
#pragma unroll
        for (int nf = 0; nf < 4; ++nf)
          acc[mf][nf] = __builtin_amdgcn_mfma_f32_16x16x32_bf16(af[mf], bfr[nf], acc[mf][nf], 0, 0, 0);
      __syncthreads();
    }
  }

#pragma unroll
  for (int mf = 0; mf < 4; ++mf) {
#pragma unroll
    for (int nf = 0; nf < 4; ++nf) {
      f32x4 v = acc[mf][nf];
      int m = m0 + wm * 64 + mf * 16 + lc * 4;
      int n = n0 + wn * 64 + nf * 16 + lr;
      if constexpr (WR_FOUT) {
        int64_t off = rmBatch * b + (int64_t)m * rmStride + n;
        float* p = orm + off;
        const float* pr = frs + off;
        U16x4 yv = *(const U16x4*)(fyt + ((int64_t)(b * 4096 + n)) * 512 + m);
        const u16* yp = (const u16*)&yv;
#pragma unroll
        for (int r = 0; r < 4; ++r) {
          float g = 1.f / (1.f + __expf(-v[r]));
          p[(int64_t)r * rmStride] =
              g * pr[(int64_t)r * rmStride] + (1.f - g) * bf2f(yp[r]);
        }
      }
      if constexpr (WR_RM) {
        float* p = orm + splitOut * split + rmBatch * b + (int64_t)m * rmStride + n;
#pragma unroll
        for (int r = 0; r < 4; ++r) p[(int64_t)r * rmStride] = v[r];
      }
      if constexpr (WR_TR) {
        U16x4 pk{f2bf(v[0]), f2bf(v[1]), f2bf(v[2]), f2bf(v[3])};
        *(U16x4*)(otr + trBatch * b + (int64_t)n * trStride + m) = pk;
      }
    }
  }
}

// ---------------------------------------------------------------------------
// weight converts + zero page
// ---------------------------------------------------------------------------
__global__ void k_zero4(uint32_t* __restrict__ p) { p[threadIdx.x] = 0u; }

__global__ void k_conv_wqkv(const float* __restrict__ w, u16* __restrict__ o) {
  int idx = blockIdx.x * 256 + threadIdx.x;           // 768*2304
  if (idx >= 768 * 2304) return;
  int oc = idx / 2304, r = idx % 2304;
  int t = r >> 8, ic = r & 255;
  int kh = t / 3, kw = t % 3;
  o[idx] = f2bf(w[((oc * 256 + ic) * 3 + kh) * 3 + kw]);
}
__global__ void k_conv_wmod(const float* __restrict__ w, u16* __restrict__ o) {
  int idx = blockIdx.x * 256 + threadIdx.x;           // 512*768
  if (idx >= 512 * 768) return;
  int oc = idx / 768, r = idx % 768;
  int t = r >> 8, ic = r & 255;
  o[idx] = f2bf(w[(oc * 256 + ic) * 3 + t]);
}
__global__ void k_convert(const float* __restrict__ in, u16* __restrict__ o, int n) {
  int idx = blockIdx.x * 256 + threadIdx.x;
  if (idx < n) o[idx] = f2bf(in[idx]);
}

// ---------------------------------------------------------------------------
// x (B,256,4096) f32 -> ycatT[b][l][256+c] bf16 (x part of concat buffer)
// ---------------------------------------------------------------------------
__global__ __launch_bounds__(256) void k_xT(const float* __restrict__ x, u16* __restrict__ ycat) {
  __shared__ float tile[64 * 68];
  int b = blockIdx.z, c0 = blockIdx.y * 64, l0 = blockIdx.x * 64;
  int t = threadIdx.x;
  int cc = t >> 2, part = t & 3;
  const float* xp = x + ((int64_t)(b * 256 + c0 + cc)) * 4096 + l0 + part * 16;
#pragma unroll
  for (int j = 0; j < 4; ++j) {
    F4 v = *(const F4*)(xp + j * 4);
    float* tp = &tile[cc * 68 + part * 16 + j * 4];
    tp[0] = v.x; tp[1] = v.y; tp[2] = v.z; tp[3] = v.w;
  }
  __syncthreads();
  int l = t >> 2;
  u16* op = ycat + ((int64_t)b * 4096 + l0 + l) * 512 + 256 + c0 + part * 16;
  __align__(16) u16 tmp[16];
#pragma unroll
  for (int j = 0; j < 16; ++j) tmp[j] = f2bf(tile[(part * 16 + j) * 68 + l]);
  *(V16*)(op) = *(V16*)&tmp[0];
  *(V16*)(op + 8) = *(V16*)&tmp[8];
}

// sum 64 partials per channel -> 1/S
__global__ void k_statsB64(const float* __restrict__ part, float* __restrict__ inv) {
  int idx = blockIdx.x * 256 + threadIdx.x;   // 4096 channels (b*512+m)
  float S = 0.f;
#pragma unroll
  for (int s = 0; s < 64; ++s) S += part[(int64_t)idx * 64 + s];
  inv[idx] = 1.0f / S;
}

// softmax over d of (sum split-K partials)*invSq[c]*invSk[d]*(1/16)
__global__ __launch_bounds__(256) void k_softmax_attn(
    const float* __restrict__ sc, const float* __restrict__ invS,
    u16* __restrict__ ma, int nsplit, int64_t splitOff) {
  int c = blockIdx.x, b = blockIdx.y;
  int64_t base = ((int64_t)b * 256 + c) * 256;
  int t = threadIdx.x;
  float z = 0.f;
  for (int s = 0; s < nsplit; ++s) z += sc[(int64_t)s * splitOff + base + t];
  float iq = invS[(int64_t)b * 512 + c];
  float ik = invS[(int64_t)b * 512 + 256 + t];
  z *= iq * ik * 0.0625f;
  __shared__ float red[256];
  red[t] = z; __syncthreads();
  for (int s = 128; s > 0; s >>= 1) { if (t < s) red[t] = fmaxf(red[t], red[t + s]); __syncthreads(); }
  float M = red[0]; __syncthreads();
  float p = __expf(z - M);
  red[t] = p; __syncthreads();
  for (int s = 128; s > 0; s >>= 1) { if (t < s) red[t] += red[t + s]; __syncthreads(); }
  ma[base + t] = f2bf(p / red[0]);
}

// ---------------------------------------------------------------------------
extern "C" void kernel_launch(void* const* d_in, const int* in_sizes, int n_in,
                              void* d_out, int out_size, void* d_ws, size_t ws_size,
                              hipStream_t stream) {
  (void)in_sizes; (void)n_in; (void)out_size; (void)ws_size;
  const float* x      = (const float*)d_in[0];
  const float* w_qkv  = (const float*)d_in[1];
  const float* w_mod  = (const float*)d_in[2];
  const float* w_res  = (const float*)d_in[3];
  const float* w_gate = (const float*)d_in[4];
  float* out = (float*)d_out;

  char* p = (char*)d_ws;
  auto take = [&](size_t n) { void* r = (void*)p; p += (n + 255) & ~(size_t)255; return r; };
  u16*    zpage  = (u16*)take(256);        // zero page for masked conv taps
  u16*    qkvT   = (u16*)take(50331648);   // [b][l][768] bf16 (q|k|v)
  u16*    ycatT  = (u16*)take(33554432);   // [b][l][512] bf16 (y|x)
  u16*    eT     = (u16*)take(33554432);   // [b][512ch][l] bf16 (e_q|e_k)
  float*  scores = (float*)take(16777216); // [8 splits][b][c][d] f32
  u16*    mattn  = (u16*)take(1048576);    // [b][c][d] bf16
  float*  partS  = (float*)take(1048576);  // [b*512+ch][64] partial sums
  float*  invS   = (float*)take(16384);    // [b*512+ch] 1/S
  u16*    Wa     = (u16*)take(3538944);    // 768 x 2304
  u16*    Wb     = (u16*)take(786432);     // 512 x 768
  u16*    Wg     = (u16*)take(262144);     // 256 x 512
  u16*    Wr     = (u16*)take(131072);     // 256 x 256
  float*  resb   = (float*)take(33554432); // [b][c][l] f32 (res)

  k_zero4<<<1, 64, 0, stream>>>((uint32_t*)zpage);
  k_conv_wqkv<<<6912, 256, 0, stream>>>(w_qkv, Wa);
  k_conv_wmod<<<1536, 256, 0, stream>>>(w_mod, Wb);
  k_convert<<<512, 256, 0, stream>>>(w_gate, Wg, 131072);
  k_convert<<<256, 256, 0, stream>>>(w_res, Wr, 65536);
  k_xT<<<dim3(64, 4, 8), 256, 0, stream>>>(x, ycatT);

  // qkv = conv2d(x, w_qkv): M=768 N=4096 K=9*256 -> qkvT bf16
  // BM=192 (MF=6): 4 mtiles x 16 ntiles x 8 = 512 blocks = 2 exact rounds
  gemmOv_bf16<2, 6><<<512, 512, 0, stream>>>(
      Wa, ycatT + 256, qkvT,
      2304, 512, (int64_t)4096 * 512,
      768, (int64_t)4096 * 768, 4, zpage);

  // mod = conv1d(v, w_mod) FUSED with e = exp(-relu(q*mod)):
  // M=512 N=4096 K=3*256 -> eT bf16 [b][512][l] + partS (modT eliminated)
  gemmOv_bf16<1, 8, 1><<<256, 512, 0, stream>>>(
      Wb, qkvT + 512, nullptr,
      768, 768, (int64_t)4096 * 768,
      0, 0, 2, zpage,
      qkvT, eT, partS);

  k_statsB64<<<16, 256, 0, stream>>>(partS, invS);

  // scores'[c][d] = sum_l e_q[c,l]*e_k[d,l]: M=256 N=256 K=4096, split-K x8
  gemm_bf16<0, true, false><<<dim3(2, 2, 64), 256, 0, stream>>>(
      eT, eT + (int64_t)256 * 4096, scores, nullptr,
      512, 4096, (int64_t)512 * 4096,
      4096, (int64_t)512 * 4096,
      256, (int64_t)256 * 256,
      0, 0,
      8, 512, (int64_t)8 * 256 * 256, zpage, nullptr, nullptr);

  k_softmax_attn<<<dim3(256, 8), 256, 0, stream>>>(
      scores, invS, mattn, 8, (int64_t)8 * 256 * 256);

  // y = m_attn @ v: M=256 N=4096 K=256 -> ycatT[:,0:256] bf16 only (yb gone)
  gemm_bf16<0, false, true><<<dim3(32, 2, 8), 256, 0, stream>>>(
      mattn, qkvT + 512, nullptr, ycatT,
      256, 256, (int64_t)256 * 256,
      768, (int64_t)4096 * 768,
      0, 0,
      512, (int64_t)4096 * 512,
      1, 0, 0, zpage, nullptr, nullptr);

  // res = w_res @ x: M=256 N=4096 K=256 -> resb f32
  gemm_bf16<0, true, false><<<dim3(32, 2, 8), 256, 0, stream>>>(
      Wr, ycatT + 256, resb, nullptr,
      256, 256, 0,
      512, (int64_t)4096 * 512,
      4096, (int64_t)256 * 4096,
      0, 0,
      1, 0, 0, zpage, nullptr, nullptr);

  // gate GEMM + FUSED final blend: out = sig(gpre)*res + (1-sig(gpre))*y
  // y read back as bf16 from ycatT (yb f32 round-trip eliminated)
  gemm_bf16<0, false, false, true><<<dim3(32, 2, 8), 256, 0, stream>>>(
      Wg, ycatT, out, nullptr,
      512, 512, 0,
      512, (int64_t)4096 * 512,
      4096, (int64_t)256 * 4096,
      0, 0,
      1, 0, 0, zpage, resb, ycatT);
}

// Round 14
// 248.155 us; speedup vs baseline: 1.3665x; 1.0511x over previous
//
#include <hip/hip_runtime.h>
#include <cstdint>

typedef unsigned short u16;
using bf16x8 = __attribute__((ext_vector_type(8))) short;   // 8 bf16 = 4 VGPR
using f32x4  = __attribute__((ext_vector_type(4))) float;   // MFMA acc

struct alignas(16) V16 { uint32_t a, b, c, d; };            // 16B chunk
struct alignas(8)  U16x4 { u16 a, b, c, d; };
struct alignas(16) F4 { float x, y, z, w; };

__device__ __forceinline__ u16 f2bf(float f) {              // RNE f32->bf16
  uint32_t u = __float_as_uint(f);
  u += 0x7fffu + ((u >> 16) & 1u);
  return (u16)(u >> 16);
}
__device__ __forceinline__ float bf2f(u16 h) {
  return __uint_as_float(((uint32_t)h) << 16);
}

// async global->LDS, 16B per lane; dest = wave-uniform base + lane*16 (linear)
#define GLOAD16(g, l) __builtin_amdgcn_global_load_lds(                         \
    (const __attribute__((address_space(1))) uint32_t*)(g),                     \
    (__attribute__((address_space(3))) uint32_t*)(l), 16, 0, 0)

// ===========================================================================
// Overlap-pipelined conv-GEMM (r9 structure, BM = MF*32, BN=256, BK=64 slab,
// 8 waves 2M x 4N, per-wave (MF*16)x64, acc[MF][4]).
//   Out[b][m][n] = sum_t sum_k A[m][t*256+k] * Bact[b][n+off(t)][k]
// NO intra-slab fences -> compiler interleaves ds_read<->MFMA with counted
// lgkmcnt. LDS ring-2 dbuf; boundary = vmcnt(0)+barrier per slab.
// Swizzle: 128-B rows, chunk ^= (row&7) (0-conflict), applied on global
// SOURCE + ds_read side; gload_lds dest linear (rule #21).
// FUSE=1 (conv1d only): epilogue computes e = exp(-relu(q*mod)) directly
// (partner channel in qkvT == mod channel m), writes e bf16 to
// eT[b][512][4096] and per-(channel, ntile*4+wn) partial sums via
// __shfl_xor lr-reduction -> partS[b*512+ch][64].
// ===========================================================================
template<int MODE, int MF, int FUSE = 0>
__global__ __launch_bounds__(512, 2) void gemmOv_bf16(
    const u16* __restrict__ A, const u16* __restrict__ B, u16* __restrict__ otr,
    int sA, int sB, int64_t bBatch, int trStride, int64_t trBatch, int MT,
    const u16* __restrict__ zpage,
    const u16* __restrict__ fq = nullptr, u16* __restrict__ eOut = nullptr,
    float* __restrict__ partS = nullptr)
{
  constexpr int NS = (MODE == 2) ? 36 : 12;    // BK=64 slabs: NTAPS*(256/64)
  constexpr int ASL = MF * 2048;               // A slab u16 (BM*64)
  constexpr int SLAB = ASL + 16384;            // + B slab (256*64)
  __shared__ __align__(16) u16 lds[2 * SLAB];

  const int tid = threadIdx.x;
  const int q = gridDim.x >> 3;                // XCD-aware bijective swizzle
  const int flat = (blockIdx.x & 7) * q + (blockIdx.x >> 3);
  const int per_b = MT * 16;                   // 16 n-tiles of 256
  const int b = flat / per_b, rem = flat % per_b;
  const int ntile = rem / MT, mtile = rem % MT;
  const int m0 = mtile * (MF * 32), n0 = ntile * 256;
  const u16* Bb = B + (int64_t)b * bBatch;

  const int lane = tid & 63, wave = tid >> 6;
  const int wm = wave >> 2, wn = wave & 3;     // 2M x 4N waves
  const int lr = lane & 15, lc = lane >> 4;

  const int lrow8 = lane >> 3;
  const int sch  = lane & 7;
  const int scs  = sch ^ (lrow8 & 7);
  const u16* aSrc[MF / 2];
  const u16* bSrc[4];
  int bRow[4];
#pragma unroll
  for (int j = 0; j < MF / 2; ++j)
    aSrc[j] = A + (int64_t)(m0 + wave * (MF * 4) + j * 8 + lrow8) * sA + scs * 8;
#pragma unroll
  for (int j = 0; j < 4; ++j) {
    bRow[j] = n0 + wave * 32 + j * 8 + lrow8;
    bSrc[j] = Bb + (int64_t)bRow[j] * sB + scs * 8;
  }

  auto stageA = [&](int s) {                   // MF/2 loads/thread
    const int kOff = (s >> 2) * 256 + ((s & 3) << 6);
    u16* dst = lds + (s & 1) * SLAB + wave * (MF / 2) * 512;
#pragma unroll
    for (int j = 0; j < MF / 2; ++j)
      GLOAD16(aSrc[j] + kOff, dst + j * 512);
  };
  auto stageB = [&](int s) {                   // 4 loads/thread (tap-masked)
    const int tap = s >> 2, kc = (s & 3) << 6;
    int off, dh = 0, dw = 0;
    if constexpr (MODE == 2) { dh = tap / 3 - 1; dw = tap % 3 - 1; off = dh * 64 + dw; }
    else                     { off = tap - 1; }
    u16* dst = lds + (s & 1) * SLAB + ASL + wave * 2048;
#pragma unroll
    for (int j = 0; j < 4; ++j) {
      bool ok;
      if constexpr (MODE == 2) {
        int hh = (bRow[j] >> 6) + dh, ww = (bRow[j] & 63) + dw;
        ok = ((unsigned)hh < 64u) && ((unsigned)ww < 64u);
      } else {
        ok = ((unsigned)(bRow[j] + off) < 4096u);
      }
      const u16* src = ok ? (bSrc[j] + (int64_t)off * sB + kc) : zpage;
      GLOAD16(src, dst + j * 512);
    }
  };

  f32x4 acc[MF][4];
#pragma unroll
  for (int i = 0; i < MF; ++i)
#pragma unroll
    for (int j = 0; j < 4; ++j) acc[i][j] = f32x4{0.f, 0.f, 0.f, 0.f};

  stageA(0); stageB(0);
  asm volatile("s_waitcnt vmcnt(0)" ::: "memory");
  __builtin_amdgcn_s_barrier();
  __builtin_amdgcn_sched_barrier(0);

  for (int s = 0; s < NS; ++s) {
    const u16* As = lds + (s & 1) * SLAB;
    const u16* Bs = As + ASL;
    const bool pf = (s + 1 < NS);
    bf16x8 bfr[4], af[MF];

    // ---- k-half 0: reads + stage A(s+1) + MF*4 MFMA (compiler-interleaved)
#pragma unroll
    for (int nf = 0; nf < 4; ++nf) {
      int row = wn * 64 + nf * 16 + lr;
      bfr[nf] = *(const bf16x8*)&Bs[row * 64 + ((lc ^ (row & 7)) * 8)];
    }
#pragma unroll
    for (int mf = 0; mf < MF; ++mf) {
      int row = wm * (MF * 16) + mf * 16 + lr;
      af[mf] = *(const bf16x8*)&As[row * 64 + ((lc ^ (row & 7)) * 8)];
    }
    if (pf) stageA(s + 1);
#pragma unroll
    for (int mf = 0; mf < MF; ++mf)
#pragma unroll
      for (int nf = 0; nf < 4; ++nf)
        acc[mf][nf] = __builtin_amdgcn_mfma_f32_16x16x32_bf16(af[mf], bfr[nf], acc[mf][nf], 0, 0, 0);

    // ---- k-half 1: reads + stage B(s+1) + MF*4 MFMA
#pragma unroll
    for (int nf = 0; nf < 4; ++nf) {
      int row = wn * 64 + nf * 16 + lr;
      bfr[nf] = *(const bf16x8*)&Bs[row * 64 + (((4 + lc) ^ (row & 7)) * 8)];
    }
#pragma unroll
    for (int mf = 0; mf < MF; ++mf) {
      int row = wm * (MF * 16) + mf * 16 + lr;
      af[mf] = *(const bf16x8*)&As[row * 64 + (((4 + lc) ^ (row & 7)) * 8)];
    }
    if (pf) stageB(s + 1);
#pragma unroll
    for (int mf = 0; mf < MF; ++mf)
#pragma unroll
      for (int nf = 0; nf < 4; ++nf)
        acc[mf][nf] = __builtin_amdgcn_mfma_f32_16x16x32_bf16(af[mf], bfr[nf], acc[mf][nf], 0, 0, 0);

    if (pf) {
      asm volatile("s_waitcnt vmcnt(0)" ::: "memory");
      __builtin_amdgcn_s_barrier();
      __builtin_amdgcn_sched_barrier(0);
    }
  }

  if constexpr (FUSE) {
    // fused e = exp(-relu(q * mod)) epilogue + deterministic partial sums
    const u16* qk = fq + (int64_t)b * 4096 * 768;
    u16* eb = eOut + (int64_t)b * 512 * 4096;
    float* ps = partS + (int64_t)b * 512 * 64;
#pragma unroll
    for (int mf = 0; mf < MF; ++mf) {
      const int mbase = m0 + wm * (MF * 16) + mf * 16 + lc * 4;
      float sp[4] = {0.f, 0.f, 0.f, 0.f};
#pragma unroll
      for (int nf = 0; nf < 4; ++nf) {
        int n = n0 + wn * 64 + nf * 16 + lr;
        U16x4 qv = *(const U16x4*)(qk + (int64_t)n * 768 + mbase);
        const u16* qp = (const u16*)&qv;
        f32x4 v = acc[mf][nf];
#pragma unroll
        for (int r = 0; r < 4; ++r) {
          float z = bf2f(qp[r]) * v[r];
          float e = __expf(z > 0.f ? -z : 0.f);
          sp[r] += e;
          eb[(int64_t)(mbase + r) * 4096 + n] = f2bf(e);
        }
      }
#pragma unroll
      for (int r = 0; r < 4; ++r) {
        float sv = sp[r];
        sv += __shfl_xor(sv, 1);
        sv += __shfl_xor(sv, 2);
        sv += __shfl_xor(sv, 4);
        sv += __shfl_xor(sv, 8);
        if (lr == 0)
          ps[(int64_t)(mbase + r) * 64 + ntile * 4 + wn] = sv;
      }
    }
  } else {
    // epilogue: C/D layout col=lane&15, row=(lane>>4)*4+reg; write transposed
#pragma unroll
    for (int mf = 0; mf < MF; ++mf)
#pragma unroll
      for (int nf = 0; nf < 4; ++nf) {
        f32x4 v = acc[mf][nf];
        int m = m0 + wm * (MF * 16) + mf * 16 + lc * 4;
        int n = n0 + wn * 64 + nf * 16 + lr;
        U16x4 pk{f2bf(v[0]), f2bf(v[1]), f2bf(v[2]), f2bf(v[3])};
        *(U16x4*)(otr + trBatch * b + (int64_t)n * trStride + m) = pk;
      }
  }
}

// ---------------------------------------------------------------------------
// 128x128 GEMM (dense stages: scores, y, gate).
// WR_FOUT+DUAL: dual-accumulator gate+res fusion. A = Wg (K=512 over
// ycatT=[y|x]); A2 = Wr (K=256, x-part only, i.e. kc in [256,512)).
// Epilogue: out = sig(gpre)*res + (1-sig(gpre))*y (y bf16 from ycatT).
// Eliminates the separate res GEMM and the resb f32 round-trip.
// ---------------------------------------------------------------------------
template<int MODE, bool WR_RM, bool WR_TR, bool WR_FOUT = false, bool DUAL = false>
__global__ __launch_bounds__(256) void gemm_bf16(
    const u16* __restrict__ A, const u16* __restrict__ B,
    float* __restrict__ orm, u16* __restrict__ otr,
    int Kc, int sA, int64_t aBatch,
    int sB, int64_t bBatch,
    int rmStride, int64_t rmBatch,
    int trStride, int64_t trBatch,
    int nsplit, int kStep, int64_t splitOut,
    const u16* __restrict__ zpage,
    const u16* __restrict__ fyt, const u16* __restrict__ A2)
{
  constexpr int NTAPS = (MODE == 2) ? 9 : (MODE == 1 ? 3 : 1);
  __shared__ __align__(16) u16 As[128 * 32];
  __shared__ __align__(16) u16 Bs[128 * 32];
  __shared__ __align__(16) u16 As2[128 * 32];   // DUAL only (Wr tile)

  const int tid = threadIdx.x;
  int b = blockIdx.z, split = 0;
  if (nsplit > 1) { split = b % nsplit; b /= nsplit; }
  const int m0  = blockIdx.y * 128;
  const int n0  = blockIdx.x * 128;
  const int lane = tid & 63, wave = tid >> 6;
  const int wm = wave >> 1, wn = wave & 1;
  const int lr = lane & 15, lc = lane >> 4;

  f32x4 acc[4][4];
#pragma unroll
  for (int i = 0; i < 4; ++i)
#pragma unroll
    for (int j = 0; j < 4; ++j) acc[i][j] = f32x4{0.f, 0.f, 0.f, 0.f};
  f32x4 acc2[4][4];
  if constexpr (DUAL) {
#pragma unroll
    for (int i = 0; i < 4; ++i)
#pragma unroll
      for (int j = 0; j < 4; ++j) acc2[i][j] = f32x4{0.f, 0.f, 0.f, 0.f};
  }

  const u16* Ab = A + (int64_t)b * aBatch + split * kStep;
  const u16* Bb = B + (int64_t)b * bBatch + split * kStep;

  const int srow = tid >> 2;
  const int sc   = tid & 3;
  const int scs  = sc ^ (srow & 3);

  for (int t = 0; t < NTAPS; ++t) {
    int dh = 0, dw = 0, off = 0;
    if constexpr (MODE == 2) { dh = t / 3 - 1; dw = t % 3 - 1; off = dh * 64 + dw; }
    if constexpr (MODE == 1) { off = t - 1; }

    for (int kc = 0; kc < Kc; kc += 32) {
      const int kA = t * Kc + kc;
      const bool dualK = DUAL && (kA >= 256);
#pragma unroll
      for (int it = 0; it < 2; ++it) {
        int row = srow + it * 64;
        GLOAD16(Ab + (int64_t)(m0 + row) * sA + kA + scs * 8,
                &As[wave * 512 + it * 2048]);
      }
      if constexpr (DUAL) {
        if (dualK) {
#pragma unroll
          for (int it = 0; it < 2; ++it) {
            int row = srow + it * 64;
            GLOAD16(A2 + (int64_t)(m0 + row) * 256 + (kA - 256) + scs * 8,
                    &As2[wave * 512 + it * 2048]);
          }
        }
      }
#pragma unroll
      for (int it = 0; it < 2; ++it) {
        int row = srow + it * 64;
        int l = n0 + row;
        int gl = l + off;
        bool ok = true;
        if constexpr (MODE == 2) {
          int hh = (l >> 6) + dh, ww = (l & 63) + dw;
          ok = ((unsigned)hh < 64u) && ((unsigned)ww < 64u);
        }
        if constexpr (MODE == 1) { ok = ((unsigned)gl < 4096u); }
        const u16* src = ok ? (Bb + (int64_t)gl * sB + kc + scs * 8) : zpage;
        GLOAD16(src, &Bs[wave * 512 + it * 2048]);
      }
      __syncthreads();

      bf16x8 af[4], bfr[4];
#pragma unroll
      for (int mf = 0; mf < 4; ++mf) {
        int row = wm * 64 + mf * 16 + lr;
        int cs = lc ^ (row & 3);
        af[mf] = *(const bf16x8*)&As[row * 32 + cs * 8];
      }
#pragma unroll
      for (int nf = 0; nf < 4; ++nf) {
        int row = wn * 64 + nf * 16 + lr;
        int cs = lc ^ (row & 3);
        bfr[nf] = *(const bf16x8*)&Bs[row * 32 + cs * 8];
      }
#pragma unroll
      for (int mf = 0; mf < 4; ++mf)
#pragma unroll
        for (int nf = 0; nf < 4; ++nf)
          acc[mf][nf] = __builtin_amdgcn_mfma_f32_16x16x32_bf16(af[mf], bfr[nf], acc[mf][nf], 0, 0, 0);
      if constexpr (DUAL) {
        if (dualK) {
          bf16x8 af2[4];
#pragma unroll
          for (int mf = 0; mf < 4; ++mf) {
            int row = wm * 64 + mf * 16 + lr;
            int cs = lc ^ (row & 3);
            af2[mf] = *(const bf16x8*)&As2[row * 32 + cs * 8];
          }
#pragma unroll
          for (int mf = 0; mf < 4; ++mf)
#pragma unroll
            for (int nf = 0; nf < 4; ++nf)
              acc2[mf][nf] = __builtin_amdgcn_mfma_f32_16x16x32_bf16(af2[mf], bfr[nf], acc2[mf][nf], 0, 0, 0);
        }
      }
      __syncthreads();
    }
  }

#pragma unroll
  for (int mf = 0; mf < 4; ++mf) {
#pragma unroll
    for (int nf = 0; nf < 4; ++nf) {
      f32x4 v = acc[mf][nf];
      int m = m0 + wm * 64 + mf * 16 + lc * 4;
      int n = n0 + wn * 64 + nf * 16 + lr;
      if constexpr (WR_FOUT) {
        int64_t off = rmBatch * b + (int64_t)m * rmStride + n;
        float* p = orm + off;
        f32x4 rv = acc2[mf][nf];
        U16x4 yv = *(const U16x4*)(fyt + ((int64_t)(b * 4096 + n)) * 512 + m);
        const u16* yp = (const u16*)&yv;
#pragma unroll
        for (int r = 0; r < 4; ++r) {
          float g = 1.f / (1.f + __expf(-v[r]));
          p[(int64_t)r * rmStride] = g * rv[r] + (1.f - g) * bf2f(yp[r]);
        }
      }
      if constexpr (WR_RM) {
        float* p = orm + splitOut * split + rmBatch * b + (int64_t)m * rmStride + n;
#pragma unroll
        for (int r = 0; r < 4; ++r) p[(int64_t)r * rmStride] = v[r];
      }
      if constexpr (WR_TR) {
        U16x4 pk{f2bf(v[0]), f2bf(v[1]), f2bf(v[2]), f2bf(v[3])};
        *(U16x4*)(otr + trBatch * b + (int64_t)n * trStride + m) = pk;
      }
    }
  }
}

// ---------------------------------------------------------------------------
// merged prep: all weight converts + zero page in ONE kernel (launch fusion)
// ---------------------------------------------------------------------------
__global__ void k_prep(const float* __restrict__ wqkv, const float* __restrict__ wmod,
                       const float* __restrict__ wgate, const float* __restrict__ wres,
                       u16* __restrict__ Wa, u16* __restrict__ Wb,
                       u16* __restrict__ Wg, u16* __restrict__ Wr,
                       uint32_t* __restrict__ zpage) {
  int bid = blockIdx.x, t = threadIdx.x;
  if (bid < 6912) {                           // Wa: 768 x (9*256)
    int idx = bid * 256 + t;
    if (idx < 768 * 2304) {
      int oc = idx / 2304, r = idx % 2304;
      int tap = r >> 8, ic = r & 255;
      Wa[idx] = f2bf(wqkv[((oc * 256 + ic) * 3 + tap / 3) * 3 + tap % 3]);
    }
  } else if (bid < 8448) {                    // Wb: 512 x (3*256)
    int idx = (bid - 6912) * 256 + t;
    if (idx < 512 * 768) {
      int oc = idx / 768, r = idx % 768;
      int tap = r >> 8, ic = r & 255;
      Wb[idx] = f2bf(wmod[(oc * 256 + ic) * 3 + tap]);
    }
  } else if (bid < 8960) {                    // Wg: 256 x 512
    int idx = (bid - 8448) * 256 + t;
    if (idx < 131072) Wg[idx] = f2bf(wgate[idx]);
  } else if (bid < 9216) {                    // Wr: 256 x 256
    int idx = (bid - 8960) * 256 + t;
    if (idx < 65536) Wr[idx] = f2bf(wres[idx]);
  } else {                                    // zero page (256 B)
    if (t < 64) zpage[t] = 0u;
  }
}

// ---------------------------------------------------------------------------
// x (B,256,4096) f32 -> ycatT[b][l][256+c] bf16 (x part of concat buffer)
// ---------------------------------------------------------------------------
__global__ __launch_bounds__(256) void k_xT(const float* __restrict__ x, u16* __restrict__ ycat) {
  __shared__ float tile[64 * 68];
  int b = blockIdx.z, c0 = blockIdx.y * 64, l0 = blockIdx.x * 64;
  int t = threadIdx.x;
  int cc = t >> 2, part = t & 3;
  const float* xp = x + ((int64_t)(b * 256 + c0 + cc)) * 4096 + l0 + part * 16;
#pragma unroll
  for (int j = 0; j < 4; ++j) {
    F4 v = *(const F4*)(xp + j * 4);
    float* tp = &tile[cc * 68 + part * 16 + j * 4];
    tp[0] = v.x; tp[1] = v.y; tp[2] = v.z; tp[3] = v.w;
  }
  __syncthreads();
  int l = t >> 2;
  u16* op = ycat + ((int64_t)b * 4096 + l0 + l) * 512 + 256 + c0 + part * 16;
  __align__(16) u16 tmp[16];
#pragma unroll
  for (int j = 0; j < 16; ++j) tmp[j] = f2bf(tile[(part * 16 + j) * 68 + l]);
  *(V16*)(op) = *(V16*)&tmp[0];
  *(V16*)(op + 8) = *(V16*)&tmp[8];
}

// sum 64 partials per channel -> 1/S
__global__ void k_statsB64(const float* __restrict__ part, float* __restrict__ inv) {
  int idx = blockIdx.x * 256 + threadIdx.x;   // 4096 channels (b*512+m)
  float S = 0.f;
#pragma unroll
  for (int s = 0; s < 64; ++s) S += part[(int64_t)idx * 64 + s];
  inv[idx] = 1.0f / S;
}

// softmax over d of (sum split-K partials)*invSq[c]*invSk[d]*(1/16)
__global__ __launch_bounds__(256) void k_softmax_attn(
    const float* __restrict__ sc, const float* __restrict__ invS,
    u16* __restrict__ ma, int nsplit, int64_t splitOff) {
  int c = blockIdx.x, b = blockIdx.y;
  int64_t base = ((int64_t)b * 256 + c) * 256;
  int t = threadIdx.x;
  float z = 0.f;
  for (int s = 0; s < nsplit; ++s) z += sc[(int64_t)s * splitOff + base + t];
  float iq = invS[(int64_t)b * 512 + c];
  float ik = invS[(int64_t)b * 512 + 256 + t];
  z *= iq * ik * 0.0625f;
  __shared__ float red[256];
  red[t] = z; __syncthreads();
  for (int s = 128; s > 0; s >>= 1) { if (t < s) red[t] = fmaxf(red[t], red[t + s]); __syncthreads(); }
  float M = red[0]; __syncthreads();
  float p = __expf(z - M);
  red[t] = p; __syncthreads();
  for (int s = 128; s > 0; s >>= 1) { if (t < s) red[t] += red[t + s]; __syncthreads(); }
  ma[base + t] = f2bf(p / red[0]);
}

// ---------------------------------------------------------------------------
extern "C" void kernel_launch(void* const* d_in, const int* in_sizes, int n_in,
                              void* d_out, int out_size, void* d_ws, size_t ws_size,
                              hipStream_t stream) {
  (void)in_sizes; (void)n_in; (void)out_size; (void)ws_size;
  const float* x      = (const float*)d_in[0];
  const float* w_qkv  = (const float*)d_in[1];
  const float* w_mod  = (const float*)d_in[2];
  const float* w_res  = (const float*)d_in[3];
  const float* w_gate = (const float*)d_in[4];
  float* out = (float*)d_out;

  char* p = (char*)d_ws;
  auto take = [&](size_t n) { void* r = (void*)p; p += (n + 255) & ~(size_t)255; return r; };
  u16*    zpage  = (u16*)take(256);        // zero page for masked conv taps
  u16*    qkvT   = (u16*)take(50331648);   // [b][l][768] bf16 (q|k|v)
  u16*    ycatT  = (u16*)take(33554432);   // [b][l][512] bf16 (y|x)
  u16*    eT     = (u16*)take(33554432);   // [b][512ch][l] bf16 (e_q|e_k)
  float*  scores = (float*)take(16777216); // [8 splits][b][c][d] f32
  u16*    mattn  = (u16*)take(1048576);    // [b][c][d] bf16
  float*  partS  = (float*)take(1048576);  // [b*512+ch][64] partial sums
  float*  invS   = (float*)take(16384);    // [b*512+ch] 1/S
  u16*    Wa     = (u16*)take(3538944);    // 768 x 2304
  u16*    Wb     = (u16*)take(786432);     // 512 x 768
  u16*    Wg     = (u16*)take(262144);     // 256 x 512
  u16*    Wr     = (u16*)take(131072);     // 256 x 256

  // all weight converts + zpage in one launch
  k_prep<<<9217, 256, 0, stream>>>(w_qkv, w_mod, w_gate, w_res,
                                   Wa, Wb, Wg, Wr, (uint32_t*)zpage);
  k_xT<<<dim3(64, 4, 8), 256, 0, stream>>>(x, ycatT);

  // qkv = conv2d(x, w_qkv): M=768 N=4096 K=9*256 -> qkvT bf16
  // BM=192 (MF=6): 4 mtiles x 16 ntiles x 8 = 512 blocks = 2 exact rounds
  gemmOv_bf16<2, 6><<<512, 512, 0, stream>>>(
      Wa, ycatT + 256, qkvT,
      2304, 512, (int64_t)4096 * 512,
      768, (int64_t)4096 * 768, 4, zpage);

  // mod = conv1d(v, w_mod) FUSED with e = exp(-relu(q*mod)):
  // M=512 N=4096 K=3*256 -> eT bf16 [b][512][l] + partS
  gemmOv_bf16<1, 8, 1><<<256, 512, 0, stream>>>(
      Wb, qkvT + 512, nullptr,
      768, 768, (int64_t)4096 * 768,
      0, 0, 2, zpage,
      qkvT, eT, partS);

  k_statsB64<<<16, 256, 0, stream>>>(partS, invS);

  // scores'[c][d] = sum_l e_q[c,l]*e_k[d,l]: M=256 N=256 K=4096, split-K x8
  gemm_bf16<0, true, false><<<dim3(2, 2, 64), 256, 0, stream>>>(
      eT, eT + (int64_t)256 * 4096, scores, nullptr,
      512, 4096, (int64_t)512 * 4096,
      4096, (int64_t)512 * 4096,
      256, (int64_t)256 * 256,
      0, 0,
      8, 512, (int64_t)8 * 256 * 256, zpage, nullptr, nullptr);

  k_softmax_attn<<<dim3(256, 8), 256, 0, stream>>>(
      scores, invS, mattn, 8, (int64_t)8 * 256 * 256);

  // y = m_attn @ v: M=256 N=4096 K=256 -> ycatT[:,0:256] bf16
  gemm_bf16<0, false, true><<<dim3(32, 2, 8), 256, 0, stream>>>(
      mattn, qkvT + 512, nullptr, ycatT,
      256, 256, (int64_t)256 * 256,
      768, (int64_t)4096 * 768,
      0, 0,
      512, (int64_t)4096 * 512,
      1, 0, 0, zpage, nullptr, nullptr);

  // gate GEMM + DUAL res + FUSED blend: gpre = Wg@[y;x]; res = Wr@x;
  // out = sig(gpre)*res + (1-sig(gpre))*y   (res GEMM + resb eliminated)
  gemm_bf16<0, false, false, true, true><<<dim3(32, 2, 8), 256, 0, stream>>>(
      Wg, ycatT, out, nullptr,
      512, 512, 0,
      512, (int64_t)4096 * 512,
      4096, (int64_t)256 * 4096,
      0, 0,
      1, 0, 0, zpage, ycatT, Wr);
}

// Round 15
// 225.690 us; speedup vs baseline: 1.5025x; 1.0995x over previous
//
#include <hip/hip_runtime.h>
#include <cstdint>

typedef unsigned short u16;
using bf16x8 = __attribute__((ext_vector_type(8))) short;   // 8 bf16 = 4 VGPR
using f32x4  = __attribute__((ext_vector_type(4))) float;   // MFMA acc

struct alignas(16) V16 { uint32_t a, b, c, d; };            // 16B chunk
struct alignas(8)  U16x4 { u16 a, b, c, d; };
struct alignas(16) F4 { float x, y, z, w; };

__device__ __forceinline__ u16 f2bf(float f) {              // RNE f32->bf16
  uint32_t u = __float_as_uint(f);
  u += 0x7fffu + ((u >> 16) & 1u);
  return (u16)(u >> 16);
}
__device__ __forceinline__ float bf2f(u16 h) {
  return __uint_as_float(((uint32_t)h) << 16);
}

// async global->LDS, 16B per lane; dest = wave-uniform base + lane*16 (linear)
#define GLOAD16(g, l) __builtin_amdgcn_global_load_lds(                         \
    (const __attribute__((address_space(1))) uint32_t*)(g),                     \
    (__attribute__((address_space(3))) uint32_t*)(l), 16, 0, 0)

// ===========================================================================
// Overlap-pipelined conv-GEMM (r9 structure, BM = MF*32, BN=256, BK=64 slab,
// 8 waves 2M x 4N, per-wave (MF*16)x64, acc[MF][4]).
//   Out[b][m][n] = sum_t sum_k A[m][t*256+k] * Bact[b][n+off(t)][k]
// NO intra-slab fences -> compiler interleaves ds_read<->MFMA with counted
// lgkmcnt. LDS ring-2 dbuf; boundary = vmcnt(0)+barrier per slab.
// Swizzle: 128-B rows, chunk ^= (row&7) (0-conflict), applied on global
// SOURCE + ds_read side; gload_lds dest linear (rule #21).
// FUSE=1 (conv1d only): epilogue computes e = exp(-relu(q*mod)), writes eT
// bf16 [b][512][4096] + per-(ch, ntile*4+wn) partial sums via __shfl_xor.
// ===========================================================================
template<int MODE, int MF, int FUSE = 0>
__global__ __launch_bounds__(512, 2) void gemmOv_bf16(
    const u16* __restrict__ A, const u16* __restrict__ B, u16* __restrict__ otr,
    int sA, int sB, int64_t bBatch, int trStride, int64_t trBatch, int MT,
    const u16* __restrict__ zpage,
    const u16* __restrict__ fq = nullptr, u16* __restrict__ eOut = nullptr,
    float* __restrict__ partS = nullptr)
{
  constexpr int NS = (MODE == 2) ? 36 : 12;    // BK=64 slabs: NTAPS*(256/64)
  constexpr int ASL = MF * 2048;               // A slab u16 (BM*64)
  constexpr int SLAB = ASL + 16384;            // + B slab (256*64)
  __shared__ __align__(16) u16 lds[2 * SLAB];

  const int tid = threadIdx.x;
  const int q = gridDim.x >> 3;                // XCD-aware bijective swizzle
  const int flat = (blockIdx.x & 7) * q + (blockIdx.x >> 3);
  const int per_b = MT * 16;                   // 16 n-tiles of 256
  const int b = flat / per_b, rem = flat % per_b;
  const int ntile = rem / MT, mtile = rem % MT;
  const int m0 = mtile * (MF * 32), n0 = ntile * 256;
  const u16* Bb = B + (int64_t)b * bBatch;

  const int lane = tid & 63, wave = tid >> 6;
  const int wm = wave >> 2, wn = wave & 3;     // 2M x 4N waves
  const int lr = lane & 15, lc = lane >> 4;

  const int lrow8 = lane >> 3;
  const int sch  = lane & 7;
  const int scs  = sch ^ (lrow8 & 7);
  const u16* aSrc[MF / 2];
  const u16* bSrc[4];
  int bRow[4];
#pragma unroll
  for (int j = 0; j < MF / 2; ++j)
    aSrc[j] = A + (int64_t)(m0 + wave * (MF * 4) + j * 8 + lrow8) * sA + scs * 8;
#pragma unroll
  for (int j = 0; j < 4; ++j) {
    bRow[j] = n0 + wave * 32 + j * 8 + lrow8;
    bSrc[j] = Bb + (int64_t)bRow[j] * sB + scs * 8;
  }

  auto stageA = [&](int s) {                   // MF/2 loads/thread
    const int kOff = (s >> 2) * 256 + ((s & 3) << 6);
    u16* dst = lds + (s & 1) * SLAB + wave * (MF / 2) * 512;
#pragma unroll
    for (int j = 0; j < MF / 2; ++j)
      GLOAD16(aSrc[j] + kOff, dst + j * 512);
  };
  auto stageB = [&](int s) {                   // 4 loads/thread (tap-masked)
    const int tap = s >> 2, kc = (s & 3) << 6;
    int off, dh = 0, dw = 0;
    if constexpr (MODE == 2) { dh = tap / 3 - 1; dw = tap % 3 - 1; off = dh * 64 + dw; }
    else                     { off = tap - 1; }
    u16* dst = lds + (s & 1) * SLAB + ASL + wave * 2048;
#pragma unroll
    for (int j = 0; j < 4; ++j) {
      bool ok;
      if constexpr (MODE == 2) {
        int hh = (bRow[j] >> 6) + dh, ww = (bRow[j] & 63) + dw;
        ok = ((unsigned)hh < 64u) && ((unsigned)ww < 64u);
      } else {
        ok = ((unsigned)(bRow[j] + off) < 4096u);
      }
      const u16* src = ok ? (bSrc[j] + (int64_t)off * sB + kc) : zpage;
      GLOAD16(src, dst + j * 512);
    }
  };

  f32x4 acc[MF][4];
#pragma unroll
  for (int i = 0; i < MF; ++i)
#pragma unroll
    for (int j = 0; j < 4; ++j) acc[i][j] = f32x4{0.f, 0.f, 0.f, 0.f};

  stageA(0); stageB(0);
  asm volatile("s_waitcnt vmcnt(0)" ::: "memory");
  __builtin_amdgcn_s_barrier();
  __builtin_amdgcn_sched_barrier(0);

  for (int s = 0; s < NS; ++s) {
    const u16* As = lds + (s & 1) * SLAB;
    const u16* Bs = As + ASL;
    const bool pf = (s + 1 < NS);
    bf16x8 bfr[4], af[MF];

#pragma unroll
    for (int nf = 0; nf < 4; ++nf) {
      int row = wn * 64 + nf * 16 + lr;
      bfr[nf] = *(const bf16x8*)&Bs[row * 64 + ((lc ^ (row & 7)) * 8)];
    }
#pragma unroll
    for (int mf = 0; mf < MF; ++mf) {
      int row = wm * (MF * 16) + mf * 16 + lr;
      af[mf] = *(const bf16x8*)&As[row * 64 + ((lc ^ (row & 7)) * 8)];
    }
    if (pf) stageA(s + 1);
#pragma unroll
    for (int mf = 0; mf < MF; ++mf)
#pragma unroll
      for (int nf = 0; nf < 4; ++nf)
        acc[mf][nf] = __builtin_amdgcn_mfma_f32_16x16x32_bf16(af[mf], bfr[nf], acc[mf][nf], 0, 0, 0);

#pragma unroll
    for (int nf = 0; nf < 4; ++nf) {
      int row = wn * 64 + nf * 16 + lr;
      bfr[nf] = *(const bf16x8*)&Bs[row * 64 + (((4 + lc) ^ (row & 7)) * 8)];
    }
#pragma unroll
    for (int mf = 0; mf < MF; ++mf) {
      int row = wm * (MF * 16) + mf * 16 + lr;
      af[mf] = *(const bf16x8*)&As[row * 64 + (((4 + lc) ^ (row & 7)) * 8)];
    }
    if (pf) stageB(s + 1);
#pragma unroll
    for (int mf = 0; mf < MF; ++mf)
#pragma unroll
      for (int nf = 0; nf < 4; ++nf)
        acc[mf][nf] = __builtin_amdgcn_mfma_f32_16x16x32_bf16(af[mf], bfr[nf], acc[mf][nf], 0, 0, 0);

    if (pf) {
      asm volatile("s_waitcnt vmcnt(0)" ::: "memory");
      __builtin_amdgcn_s_barrier();
      __builtin_amdgcn_sched_barrier(0);
    }
  }

  if constexpr (FUSE) {
    const u16* qk = fq + (int64_t)b * 4096 * 768;
    u16* eb = eOut + (int64_t)b * 512 * 4096;
    float* ps = partS + (int64_t)b * 512 * 64;
#pragma unroll
    for (int mf = 0; mf < MF; ++mf) {
      const int mbase = m0 + wm * (MF * 16) + mf * 16 + lc * 4;
      float sp[4] = {0.f, 0.f, 0.f, 0.f};
#pragma unroll
      for (int nf = 0; nf < 4; ++nf) {
        int n = n0 + wn * 64 + nf * 16 + lr;
        U16x4 qv = *(const U16x4*)(qk + (int64_t)n * 768 + mbase);
        const u16* qp = (const u16*)&qv;
        f32x4 v = acc[mf][nf];
#pragma unroll
        for (int r = 0; r < 4; ++r) {
          float z = bf2f(qp[r]) * v[r];
          float e = __expf(z > 0.f ? -z : 0.f);
          sp[r] += e;
          eb[(int64_t)(mbase + r) * 4096 + n] = f2bf(e);
        }
      }
#pragma unroll
      for (int r = 0; r < 4; ++r) {
        float sv = sp[r];
        sv += __shfl_xor(sv, 1);
        sv += __shfl_xor(sv, 2);
        sv += __shfl_xor(sv, 4);
        sv += __shfl_xor(sv, 8);
        if (lr == 0)
          ps[(int64_t)(mbase + r) * 64 + ntile * 4 + wn] = sv;
      }
    }
  } else {
#pragma unroll
    for (int mf = 0; mf < MF; ++mf)
#pragma unroll
      for (int nf = 0; nf < 4; ++nf) {
        f32x4 v = acc[mf][nf];
        int m = m0 + wm * (MF * 16) + mf * 16 + lc * 4;
        int n = n0 + wn * 64 + nf * 16 + lr;
        U16x4 pk{f2bf(v[0]), f2bf(v[1]), f2bf(v[2]), f2bf(v[3])};
        *(U16x4*)(otr + trBatch * b + (int64_t)n * trStride + m) = pk;
      }
  }
}

// ---------------------------------------------------------------------------
// scores GEMM (128x128, split-K): scores'[c][d] = sum_l e_q[c,l]*e_k[d,l]
// ---------------------------------------------------------------------------
__global__ __launch_bounds__(256) void gemm_scores(
    const u16* __restrict__ A, const u16* __restrict__ B,
    float* __restrict__ orm,
    int sA, int64_t aBatch, int sB, int64_t bBatch,
    int rmStride, int64_t rmBatch,
    int nsplit, int kStep, int64_t splitOut)
{
  __shared__ __align__(16) u16 As[128 * 32];
  __shared__ __align__(16) u16 Bs[128 * 32];

  const int tid = threadIdx.x;
  int b = blockIdx.z, split = 0;
  if (nsplit > 1) { split = b % nsplit; b /= nsplit; }
  const int m0  = blockIdx.y * 128;
  const int n0  = blockIdx.x * 128;
  const int lane = tid & 63, wave = tid >> 6;
  const int wm = wave >> 1, wn = wave & 1;
  const int lr = lane & 15, lc = lane >> 4;

  f32x4 acc[4][4];
#pragma unroll
  for (int i = 0; i < 4; ++i)
#pragma unroll
    for (int j = 0; j < 4; ++j) acc[i][j] = f32x4{0.f, 0.f, 0.f, 0.f};

  const u16* Ab = A + (int64_t)b * aBatch + split * kStep;
  const u16* Bb = B + (int64_t)b * bBatch + split * kStep;

  const int srow = tid >> 2;
  const int sc   = tid & 3;
  const int scs  = sc ^ (srow & 3);

  for (int kc = 0; kc < 512; kc += 32) {
#pragma unroll
    for (int it = 0; it < 2; ++it) {
      int row = srow + it * 64;
      GLOAD16(Ab + (int64_t)(m0 + row) * sA + kc + scs * 8,
              &As[wave * 512 + it * 2048]);
      GLOAD16(Bb + (int64_t)(n0 + row) * sB + kc + scs * 8,
              &Bs[wave * 512 + it * 2048]);
    }
    __syncthreads();

    bf16x8 af[4], bfr[4];
#pragma unroll
    for (int mf = 0; mf < 4; ++mf) {
      int row = wm * 64 + mf * 16 + lr;
      af[mf] = *(const bf16x8*)&As[row * 32 + ((lc ^ (row & 3)) * 8)];
    }
#pragma unroll
    for (int nf = 0; nf < 4; ++nf) {
      int row = wn * 64 + nf * 16 + lr;
      bfr[nf] = *(const bf16x8*)&Bs[row * 32 + ((lc ^ (row & 3)) * 8)];
    }
#pragma unroll
    for (int mf = 0; mf < 4; ++mf)
#pragma unroll
      for (int nf = 0; nf < 4; ++nf)
        acc[mf][nf] = __builtin_amdgcn_mfma_f32_16x16x32_bf16(af[mf], bfr[nf], acc[mf][nf], 0, 0, 0);
    __syncthreads();
  }

#pragma unroll
  for (int mf = 0; mf < 4; ++mf)
#pragma unroll
    for (int nf = 0; nf < 4; ++nf) {
      f32x4 v = acc[mf][nf];
      int m = m0 + wm * 64 + mf * 16 + lc * 4;
      int n = n0 + wn * 64 + nf * 16 + lr;
      float* p = orm + splitOut * split + rmBatch * b + (int64_t)m * rmStride + n;
#pragma unroll
      for (int r = 0; r < 4; ++r) p[(int64_t)r * rmStride] = v[r];
    }
}

// ===========================================================================
// k_tail: fused y = mattn@v  ->  gate = Wg@[y;x], res = Wr@x, sigmoid blend.
// One block per (l-tile of 128, batch): M=256 (all channels), 512 thr =
// 8 waves (4M x 2N of 64x64). Phase 1 computes y, transposes into LDS
// yT[128][260] (bf16, padded). Phase 2: K=512; k<256 B-frags from yT,
// k>=256 staged from ycatT x-part; dual acc2 for res (Wr). Epilogue:
// out = sig(gpre)*res + (1-sig)*y. Eliminates y global round-trip + 2
// dispatches. Grid 256 = 1 exact round.
// ===========================================================================
__global__ __launch_bounds__(512) void k_tail(
    const u16* __restrict__ mattn, const u16* __restrict__ qkvT,
    const u16* __restrict__ ycatT, const u16* __restrict__ Wg,
    const u16* __restrict__ Wr, float* __restrict__ out)
{
  __shared__ __align__(16) u16 As[256 * 32];    // 16 KB (mattn / Wg slices)
  __shared__ __align__(16) u16 As2[256 * 32];   // 16 KB (Wr slices)
  __shared__ __align__(16) u16 Bs[128 * 32];    // 8 KB  (v / x slices)
  __shared__ __align__(16) u16 yT[128 * 260];   // 65 KB (y^T, padded)

  const int b = blockIdx.y, l0 = blockIdx.x * 128;
  const int tid = threadIdx.x;
  const int lane = tid & 63, wave = tid >> 6;
  const int wm = wave >> 1, wn = wave & 1;      // 4M x 2N (wm 0..3)
  const int lr = lane & 15, lc = lane >> 4;

  const int srow = tid >> 2, sc = tid & 3;      // staging row/chunk
  const int scs = sc ^ (srow & 3);

  f32x4 acc[4][4];
#pragma unroll
  for (int i = 0; i < 4; ++i)
#pragma unroll
    for (int j = 0; j < 4; ++j) acc[i][j] = f32x4{0.f, 0.f, 0.f, 0.f};

  // ---- phase 1: y[256][128] = mattn @ v ----
  const u16* Am = mattn + (int64_t)b * 65536;
  const u16* Vv = qkvT + (int64_t)b * 4096 * 768 + 512;
  for (int kc = 0; kc < 256; kc += 32) {
#pragma unroll
    for (int it = 0; it < 2; ++it) {
      int row = srow + it * 128;                // (row&3)==(srow&3)
      GLOAD16(Am + (int64_t)row * 256 + kc + scs * 8,
              &As[wave * 512 + it * 4096]);
    }
    GLOAD16(Vv + (int64_t)(l0 + srow) * 768 + kc + scs * 8, &Bs[wave * 512]);
    __syncthreads();

    bf16x8 af[4], bfr[4];
#pragma unroll
    for (int mf = 0; mf < 4; ++mf) {
      int row = wm * 64 + mf * 16 + lr;
      af[mf] = *(const bf16x8*)&As[row * 32 + ((lc ^ (row & 3)) * 8)];
    }
#pragma unroll
    for (int nf = 0; nf < 4; ++nf) {
      int row = wn * 64 + nf * 16 + lr;
      bfr[nf] = *(const bf16x8*)&Bs[row * 32 + ((lc ^ (row & 3)) * 8)];
    }
#pragma unroll
    for (int mf = 0; mf < 4; ++mf)
#pragma unroll
      for (int nf = 0; nf < 4; ++nf)
        acc[mf][nf] = __builtin_amdgcn_mfma_f32_16x16x32_bf16(af[mf], bfr[nf], acc[mf][nf], 0, 0, 0);
    __syncthreads();
  }

  // transpose y into LDS: yT[l_local][ch] bf16 (padded stride 260)
#pragma unroll
  for (int mf = 0; mf < 4; ++mf)
#pragma unroll
    for (int nf = 0; nf < 4; ++nf) {
      f32x4 v = acc[mf][nf];
      int m = wm * 64 + mf * 16 + lc * 4;
      int n = wn * 64 + nf * 16 + lr;
      U16x4 pk{f2bf(v[0]), f2bf(v[1]), f2bf(v[2]), f2bf(v[3])};
      *(U16x4*)&yT[n * 260 + m] = pk;
    }
  __syncthreads();

  // ---- phase 2: gate (K=512) + res (K 256..511), dual accumulators ----
  f32x4 acc2[4][4];
#pragma unroll
  for (int i = 0; i < 4; ++i)
#pragma unroll
    for (int j = 0; j < 4; ++j) {
      acc[i][j] = f32x4{0.f, 0.f, 0.f, 0.f};
      acc2[i][j] = f32x4{0.f, 0.f, 0.f, 0.f};
    }

  const u16* Xc = ycatT + (int64_t)b * 4096 * 512;
  for (int kc = 0; kc < 512; kc += 32) {
    const bool xk = (kc >= 256);
#pragma unroll
    for (int it = 0; it < 2; ++it) {
      int row = srow + it * 128;
      GLOAD16(Wg + (int64_t)row * 512 + kc + scs * 8,
              &As[wave * 512 + it * 4096]);
    }
    if (xk) {
#pragma unroll
      for (int it = 0; it < 2; ++it) {
        int row = srow + it * 128;
        GLOAD16(Wr + (int64_t)row * 256 + (kc - 256) + scs * 8,
                &As2[wave * 512 + it * 4096]);
      }
      GLOAD16(Xc + (int64_t)(l0 + srow) * 512 + kc + scs * 8, &Bs[wave * 512]);
    }
    __syncthreads();

    bf16x8 af[4], bfr[4];
#pragma unroll
    for (int nf = 0; nf < 4; ++nf) {
      int row = wn * 64 + nf * 16 + lr;
      if (xk) bfr[nf] = *(const bf16x8*)&Bs[row * 32 + ((lc ^ (row & 3)) * 8)];
      else    bfr[nf] = *(const bf16x8*)&yT[row * 260 + kc + lc * 8];
    }
#pragma unroll
    for (int mf = 0; mf < 4; ++mf) {
      int row = wm * 64 + mf * 16 + lr;
      af[mf] = *(const bf16x8*)&As[row * 32 + ((lc ^ (row & 3)) * 8)];
    }
#pragma unroll
    for (int mf = 0; mf < 4; ++mf)
#pragma unroll
      for (int nf = 0; nf < 4; ++nf)
        acc[mf][nf] = __builtin_amdgcn_mfma_f32_16x16x32_bf16(af[mf], bfr[nf], acc[mf][nf], 0, 0, 0);
    if (xk) {
      bf16x8 af2[4];
#pragma unroll
      for (int mf = 0; mf < 4; ++mf) {
        int row = wm * 64 + mf * 16 + lr;
        af2[mf] = *(const bf16x8*)&As2[row * 32 + ((lc ^ (row & 3)) * 8)];
      }
#pragma unroll
      for (int mf = 0; mf < 4; ++mf)
#pragma unroll
        for (int nf = 0; nf < 4; ++nf)
          acc2[mf][nf] = __builtin_amdgcn_mfma_f32_16x16x32_bf16(af2[mf], bfr[nf], acc2[mf][nf], 0, 0, 0);
    }
    __syncthreads();
  }

  // epilogue: out = sig(gpre)*res + (1-sig)*y
#pragma unroll
  for (int mf = 0; mf < 4; ++mf)
#pragma unroll
    for (int nf = 0; nf < 4; ++nf) {
      f32x4 g4 = acc[mf][nf], r4 = acc2[mf][nf];
      int m = wm * 64 + mf * 16 + lc * 4;
      int n = wn * 64 + nf * 16 + lr;
      U16x4 yv = *(const U16x4*)&yT[n * 260 + m];
      const u16* yp = (const u16*)&yv;
      float* p = out + (int64_t)b * 256 * 4096 + (int64_t)m * 4096 + l0 + n;
#pragma unroll
      for (int r = 0; r < 4; ++r) {
        float g = 1.f / (1.f + __expf(-g4[r]));
        p[(int64_t)r * 4096] = g * r4[r] + (1.f - g) * bf2f(yp[r]);
      }
    }
}

// ---------------------------------------------------------------------------
// merged prep: all weight converts + zero page in ONE kernel
// ---------------------------------------------------------------------------
__global__ void k_prep(const float* __restrict__ wqkv, const float* __restrict__ wmod,
                       const float* __restrict__ wgate, const float* __restrict__ wres,
                       u16* __restrict__ Wa, u16* __restrict__ Wb,
                       u16* __restrict__ Wg, u16* __restrict__ Wr,
                       uint32_t* __restrict__ zpage) {
  int bid = blockIdx.x, t = threadIdx.x;
  if (bid < 6912) {                           // Wa: 768 x (9*256)
    int idx = bid * 256 + t;
    if (idx < 768 * 2304) {
      int oc = idx / 2304, r = idx % 2304;
      int tap = r >> 8, ic = r & 255;
      Wa[idx] = f2bf(wqkv[((oc * 256 + ic) * 3 + tap / 3) * 3 + tap % 3]);
    }
  } else if (bid < 8448) {                    // Wb: 512 x (3*256)
    int idx = (bid - 6912) * 256 + t;
    if (idx < 512 * 768) {
      int oc = idx / 768, r = idx % 768;
      int tap = r >> 8, ic = r & 255;
      Wb[idx] = f2bf(wmod[(oc * 256 + ic) * 3 + tap]);
    }
  } else if (bid < 8960) {                    // Wg: 256 x 512
    int idx = (bid - 8448) * 256 + t;
    if (idx < 131072) Wg[idx] = f2bf(wgate[idx]);
  } else if (bid < 9216) {                    // Wr: 256 x 256
    int idx = (bid - 8960) * 256 + t;
    if (idx < 65536) Wr[idx] = f2bf(wres[idx]);
  } else {
    if (t < 64) zpage[t] = 0u;
  }
}

// ---------------------------------------------------------------------------
// x (B,256,4096) f32 -> ycatT[b][l][256+c] bf16 (x part of concat buffer)
// ---------------------------------------------------------------------------
__global__ __launch_bounds__(256) void k_xT(const float* __restrict__ x, u16* __restrict__ ycat) {
  __shared__ float tile[64 * 68];
  int b = blockIdx.z, c0 = blockIdx.y * 64, l0 = blockIdx.x * 64;
  int t = threadIdx.x;
  int cc = t >> 2, part = t & 3;
  const float* xp = x + ((int64_t)(b * 256 + c0 + cc)) * 4096 + l0 + part * 16;
#pragma unroll
  for (int j = 0; j < 4; ++j) {
    F4 v = *(const F4*)(xp + j * 4);
    float* tp = &tile[cc * 68 + part * 16 + j * 4];
    tp[0] = v.x; tp[1] = v.y; tp[2] = v.z; tp[3] = v.w;
  }
  __syncthreads();
  int l = t >> 2;
  u16* op = ycat + ((int64_t)b * 4096 + l0 + l) * 512 + 256 + c0 + part * 16;
  __align__(16) u16 tmp[16];
#pragma unroll
  for (int j = 0; j < 16; ++j) tmp[j] = f2bf(tile[(part * 16 + j) * 68 + l]);
  *(V16*)(op) = *(V16*)&tmp[0];
  *(V16*)(op + 8) = *(V16*)&tmp[8];
}

// sum 64 partials per channel -> 1/S
__global__ void k_statsB64(const float* __restrict__ part, float* __restrict__ inv) {
  int idx = blockIdx.x * 256 + threadIdx.x;   // 4096 channels (b*512+m)
  float S = 0.f;
#pragma unroll
  for (int s = 0; s < 64; ++s) S += part[(int64_t)idx * 64 + s];
  inv[idx] = 1.0f / S;
}

// softmax over d of (sum split-K partials)*invSq[c]*invSk[d]*(1/16)
__global__ __launch_bounds__(256) void k_softmax_attn(
    const float* __restrict__ sc, const float* __restrict__ invS,
    u16* __restrict__ ma, int nsplit, int64_t splitOff) {
  int c = blockIdx.x, b = blockIdx.y;
  int64_t base = ((int64_t)b * 256 + c) * 256;
  int t = threadIdx.x;
  float z = 0.f;
  for (int s = 0; s < nsplit; ++s) z += sc[(int64_t)s * splitOff + base + t];
  float iq = invS[(int64_t)b * 512 + c];
  float ik = invS[(int64_t)b * 512 + 256 + t];
  z *= iq * ik * 0.0625f;
  __shared__ float red[256];
  red[t] = z; __syncthreads();
  for (int s = 128; s > 0; s >>= 1) { if (t < s) red[t] = fmaxf(red[t], red[t + s]); __syncthreads(); }
  float M = red[0]; __syncthreads();
  float p = __expf(z - M);
  red[t] = p; __syncthreads();
  for (int s = 128; s > 0; s >>= 1) { if (t < s) red[t] += red[t + s]; __syncthreads(); }
  ma[base + t] = f2bf(p / red[0]);
}

// ---------------------------------------------------------------------------
extern "C" void kernel_launch(void* const* d_in, const int* in_sizes, int n_in,
                              void* d_out, int out_size, void* d_ws, size_t ws_size,
                              hipStream_t stream) {
  (void)in_sizes; (void)n_in; (void)out_size; (void)ws_size;
  const float* x      = (const float*)d_in[0];
  const float* w_qkv  = (const float*)d_in[1];
  const float* w_mod  = (const float*)d_in[2];
  const float* w_res  = (const float*)d_in[3];
  const float* w_gate = (const float*)d_in[4];
  float* out = (float*)d_out;

  char* p = (char*)d_ws;
  auto take = [&](size_t n) { void* r = (void*)p; p += (n + 255) & ~(size_t)255; return r; };
  u16*    zpage  = (u16*)take(256);        // zero page for masked conv taps
  u16*    qkvT   = (u16*)take(50331648);   // [b][l][768] bf16 (q|k|v)
  u16*    ycatT  = (u16*)take(33554432);   // [b][l][512] bf16 (x in cols 256+)
  u16*    eT     = (u16*)take(33554432);   // [b][512ch][l] bf16 (e_q|e_k)
  float*  scores = (float*)take(16777216); // [8 splits][b][c][d] f32
  u16*    mattn  = (u16*)take(1048576);    // [b][c][d] bf16
  float*  partS  = (float*)take(1048576);  // [b*512+ch][64] partial sums
  float*  invS   = (float*)take(16384);    // [b*512+ch] 1/S
  u16*    Wa     = (u16*)take(3538944);    // 768 x 2304
  u16*    Wb     = (u16*)take(786432);     // 512 x 768
  u16*    Wg     = (u16*)take(262144);     // 256 x 512
  u16*    Wr     = (u16*)take(131072);     // 256 x 256

  k_prep<<<9217, 256, 0, stream>>>(w_qkv, w_mod, w_gate, w_res,
                                   Wa, Wb, Wg, Wr, (uint32_t*)zpage);
  k_xT<<<dim3(64, 4, 8), 256, 0, stream>>>(x, ycatT);

  // qkv = conv2d(x, w_qkv): M=768 N=4096 K=9*256 -> qkvT bf16
  gemmOv_bf16<2, 6><<<512, 512, 0, stream>>>(
      Wa, ycatT + 256, qkvT,
      2304, 512, (int64_t)4096 * 512,
      768, (int64_t)4096 * 768, 4, zpage);

  // mod = conv1d(v, w_mod) FUSED with e = exp(-relu(q*mod)) -> eT + partS
  gemmOv_bf16<1, 8, 1><<<256, 512, 0, stream>>>(
      Wb, qkvT + 512, nullptr,
      768, 768, (int64_t)4096 * 768,
      0, 0, 2, zpage,
      qkvT, eT, partS);

  k_statsB64<<<16, 256, 0, stream>>>(partS, invS);

  // scores'[c][d] = sum_l e_q[c,l]*e_k[d,l]: M=256 N=256 K=4096, split-K x8
  gemm_scores<<<dim3(2, 2, 64), 256, 0, stream>>>(
      eT, eT + (int64_t)256 * 4096, scores,
      4096, (int64_t)512 * 4096,
      4096, (int64_t)512 * 4096,
      256, (int64_t)256 * 256,
      8, 512, (int64_t)8 * 256 * 256);

  k_softmax_attn<<<dim3(256, 8), 256, 0, stream>>>(
      scores, invS, mattn, 8, (int64_t)8 * 256 * 256);

  // fused tail: y = mattn@v -> gate/res/blend -> out   (y round-trip gone)
  k_tail<<<dim3(32, 8), 512, 0, stream>>>(mattn, qkvT, ycatT, Wg, Wr, out);
}

// Round 16
// 218.441 us; speedup vs baseline: 1.5524x; 1.0332x over previous
//
#include <hip/hip_runtime.h>
#include <cstdint>

typedef unsigned short u16;
using bf16x8 = __attribute__((ext_vector_type(8))) short;   // 8 bf16 = 4 VGPR
using f32x4  = __attribute__((ext_vector_type(4))) float;   // MFMA acc

struct alignas(16) V16 { uint32_t a, b, c, d; };            // 16B chunk
struct alignas(8)  U16x4 { u16 a, b, c, d; };
struct alignas(16) F4 { float x, y, z, w; };

__device__ __forceinline__ u16 f2bf(float f) {              // RNE f32->bf16
  uint32_t u = __float_as_uint(f);
  u += 0x7fffu + ((u >> 16) & 1u);
  return (u16)(u >> 16);
}
__device__ __forceinline__ float bf2f(u16 h) {
  return __uint_as_float(((uint32_t)h) << 16);
}

// async global->LDS, 16B per lane; dest = wave-uniform base + lane*16 (linear)
#define GLOAD16(g, l) __builtin_amdgcn_global_load_lds(                         \
    (const __attribute__((address_space(1))) uint32_t*)(g),                     \
    (__attribute__((address_space(3))) uint32_t*)(l), 16, 0, 0)

// ===========================================================================
// Overlap-pipelined conv-GEMM (r9 structure, BM = MF*32, BN=256, BK=64 slab,
// 8 waves 2M x 4N, per-wave (MF*16)x64, acc[MF][4]).
//   Out[b][m][n] = sum_t sum_k A[m][t*256+k] * Bact[b][n+off(t)][k]
// NO intra-slab fences -> compiler interleaves ds_read<->MFMA with counted
// lgkmcnt. LDS ring-2 dbuf; boundary = vmcnt(0)+barrier per slab.
// Swizzle: 128-B rows, chunk ^= (row&7) (0-conflict), applied on global
// SOURCE + ds_read side; gload_lds dest linear (rule #21).
// T5 (r16): setprio(1) around each k-half's MFMA cluster. Mechanism
// prerequisite present: waves hit stage-issue vs MFMA-cluster at staggered
// times (fence-free), so the CU scheduler has roles to arbitrate (m224 case,
// not m190's lockstep null).
// FUSE=1 (conv1d only): epilogue computes e = exp(-relu(q*mod)), writes eT
// bf16 [b][512][4096] + per-(ch, ntile*4+wn) partial sums via __shfl_xor.
// ===========================================================================
template<int MODE, int MF, int FUSE = 0>
__global__ __launch_bounds__(512, 2) void gemmOv_bf16(
    const u16* __restrict__ A, const u16* __restrict__ B, u16* __restrict__ otr,
    int sA, int sB, int64_t bBatch, int trStride, int64_t trBatch, int MT,
    const u16* __restrict__ zpage,
    const u16* __restrict__ fq = nullptr, u16* __restrict__ eOut = nullptr,
    float* __restrict__ partS = nullptr)
{
  constexpr int NS = (MODE == 2) ? 36 : 12;    // BK=64 slabs: NTAPS*(256/64)
  constexpr int ASL = MF * 2048;               // A slab u16 (BM*64)
  constexpr int SLAB = ASL + 16384;            // + B slab (256*64)
  __shared__ __align__(16) u16 lds[2 * SLAB];

  const int tid = threadIdx.x;
  const int q = gridDim.x >> 3;                // XCD-aware bijective swizzle
  const int flat = (blockIdx.x & 7) * q + (blockIdx.x >> 3);
  const int per_b = MT * 16;                   // 16 n-tiles of 256
  const int b = flat / per_b, rem = flat % per_b;
  const int ntile = rem / MT, mtile = rem % MT;
  const int m0 = mtile * (MF * 32), n0 = ntile * 256;
  const u16* Bb = B + (int64_t)b * bBatch;

  const int lane = tid & 63, wave = tid >> 6;
  const int wm = wave >> 2, wn = wave & 3;     // 2M x 4N waves
  const int lr = lane & 15, lc = lane >> 4;

  const int lrow8 = lane >> 3;
  const int sch  = lane & 7;
  const int scs  = sch ^ (lrow8 & 7);
  const u16* aSrc[MF / 2];
  const u16* bSrc[4];
  int bRow[4];
#pragma unroll
  for (int j = 0; j < MF / 2; ++j)
    aSrc[j] = A + (int64_t)(m0 + wave * (MF * 4) + j * 8 + lrow8) * sA + scs * 8;
#pragma unroll
  for (int j = 0; j < 4; ++j) {
    bRow[j] = n0 + wave * 32 + j * 8 + lrow8;
    bSrc[j] = Bb + (int64_t)bRow[j] * sB + scs * 8;
  }

  auto stageA = [&](int s) {                   // MF/2 loads/thread
    const int kOff = (s >> 2) * 256 + ((s & 3) << 6);
    u16* dst = lds + (s & 1) * SLAB + wave * (MF / 2) * 512;
#pragma unroll
    for (int j = 0; j < MF / 2; ++j)
      GLOAD16(aSrc[j] + kOff, dst + j * 512);
  };
  auto stageB = [&](int s) {                   // 4 loads/thread (tap-masked)
    const int tap = s >> 2, kc = (s & 3) << 6;
    int off, dh = 0, dw = 0;
    if constexpr (MODE == 2) { dh = tap / 3 - 1; dw = tap % 3 - 1; off = dh * 64 + dw; }
    else                     { off = tap - 1; }
    u16* dst = lds + (s & 1) * SLAB + ASL + wave * 2048;
#pragma unroll
    for (int j = 0; j < 4; ++j) {
      bool ok;
      if constexpr (MODE == 2) {
        int hh = (bRow[j] >> 6) + dh, ww = (bRow[j] & 63) + dw;
        ok = ((unsigned)hh < 64u) && ((unsigned)ww < 64u);
      } else {
        ok = ((unsigned)(bRow[j] + off) < 4096u);
      }
      const u16* src = ok ? (bSrc[j] + (int64_t)off * sB + kc) : zpage;
      GLOAD16(src, dst + j * 512);
    }
  };

  f32x4 acc[MF][4];
#pragma unroll
  for (int i = 0; i < MF; ++i)
#pragma unroll
    for (int j = 0; j < 4; ++j) acc[i][j] = f32x4{0.f, 0.f, 0.f, 0.f};

  stageA(0); stageB(0);
  asm volatile("s_waitcnt vmcnt(0)" ::: "memory");
  __builtin_amdgcn_s_barrier();
  __builtin_amdgcn_sched_barrier(0);

  for (int s = 0; s < NS; ++s) {
    const u16* As = lds + (s & 1) * SLAB;
    const u16* Bs = As + ASL;
    const bool pf = (s + 1 < NS);
    bf16x8 bfr[4], af[MF];

    // ---- k-half 0: reads + stage A(s+1) + MF*4 MFMA (compiler-interleaved)
#pragma unroll
    for (int nf = 0; nf < 4; ++nf) {
      int row = wn * 64 + nf * 16 + lr;
      bfr[nf] = *(const bf16x8*)&Bs[row * 64 + ((lc ^ (row & 7)) * 8)];
    }
#pragma unroll
    for (int mf = 0; mf < MF; ++mf) {
      int row = wm * (MF * 16) + mf * 16 + lr;
      af[mf] = *(const bf16x8*)&As[row * 64 + ((lc ^ (row & 7)) * 8)];
    }
    if (pf) stageA(s + 1);
    __builtin_amdgcn_s_setprio(1);
#pragma unroll
    for (int mf = 0; mf < MF; ++mf)
#pragma unroll
      for (int nf = 0; nf < 4; ++nf)
        acc[mf][nf] = __builtin_amdgcn_mfma_f32_16x16x32_bf16(af[mf], bfr[nf], acc[mf][nf], 0, 0, 0);
    __builtin_amdgcn_s_setprio(0);

    // ---- k-half 1: reads + stage B(s+1) + MF*4 MFMA
#pragma unroll
    for (int nf = 0; nf < 4; ++nf) {
      int row = wn * 64 + nf * 16 + lr;
      bfr[nf] = *(const bf16x8*)&Bs[row * 64 + (((4 + lc) ^ (row & 7)) * 8)];
    }
#pragma unroll
    for (int mf = 0; mf < MF; ++mf) {
      int row = wm * (MF * 16) + mf * 16 + lr;
      af[mf] = *(const bf16x8*)&As[row * 64 + (((4 + lc) ^ (row & 7)) * 8)];
    }
    if (pf) stageB(s + 1);
    __builtin_amdgcn_s_setprio(1);
#pragma unroll
    for (int mf = 0; mf < MF; ++mf)
#pragma unroll
      for (int nf = 0; nf < 4; ++nf)
        acc[mf][nf] = __builtin_amdgcn_mfma_f32_16x16x32_bf16(af[mf], bfr[nf], acc[mf][nf], 0, 0, 0);
    __builtin_amdgcn_s_setprio(0);

    if (pf) {
      asm volatile("s_waitcnt vmcnt(0)" ::: "memory");
      __builtin_amdgcn_s_barrier();
      __builtin_amdgcn_sched_barrier(0);
    }
  }

  if constexpr (FUSE) {
    const u16* qk = fq + (int64_t)b * 4096 * 768;
    u16* eb = eOut + (int64_t)b * 512 * 4096;
    float* ps = partS + (int64_t)b * 512 * 64;
#pragma unroll
    for (int mf = 0; mf < MF; ++mf) {
      const int mbase = m0 + wm * (MF * 16) + mf * 16 + lc * 4;
      float sp[4] = {0.f, 0.f, 0.f, 0.f};
#pragma unroll
      for (int nf = 0; nf < 4; ++nf) {
        int n = n0 + wn * 64 + nf * 16 + lr;
        U16x4 qv = *(const U16x4*)(qk + (int64_t)n * 768 + mbase);
        const u16* qp = (const u16*)&qv;
        f32x4 v = acc[mf][nf];
#pragma unroll
        for (int r = 0; r < 4; ++r) {
          float z = bf2f(qp[r]) * v[r];
          float e = __expf(z > 0.f ? -z : 0.f);
          sp[r] += e;
          eb[(int64_t)(mbase + r) * 4096 + n] = f2bf(e);
        }
      }
#pragma unroll
      for (int r = 0; r < 4; ++r) {
        float sv = sp[r];
        sv += __shfl_xor(sv, 1);
        sv += __shfl_xor(sv, 2);
        sv += __shfl_xor(sv, 4);
        sv += __shfl_xor(sv, 8);
        if (lr == 0)
          ps[(int64_t)(mbase + r) * 64 + ntile * 4 + wn] = sv;
      }
    }
  } else {
#pragma unroll
    for (int mf = 0; mf < MF; ++mf)
#pragma unroll
      for (int nf = 0; nf < 4; ++nf) {
        f32x4 v = acc[mf][nf];
        int m = m0 + wm * (MF * 16) + mf * 16 + lc * 4;
        int n = n0 + wn * 64 + nf * 16 + lr;
        U16x4 pk{f2bf(v[0]), f2bf(v[1]), f2bf(v[2]), f2bf(v[3])};
        *(U16x4*)(otr + trBatch * b + (int64_t)n * trStride + m) = pk;
      }
  }
}

// ---------------------------------------------------------------------------
// scores GEMM (128x128, split-K): scores'[c][d] = sum_l e_q[c,l]*e_k[d,l]
// ---------------------------------------------------------------------------
__global__ __launch_bounds__(256) void gemm_scores(
    const u16* __restrict__ A, const u16* __restrict__ B,
    float* __restrict__ orm,
    int sA, int64_t aBatch, int sB, int64_t bBatch,
    int rmStride, int64_t rmBatch,
    int nsplit, int kStep, int64_t splitOut)
{
  __shared__ __align__(16) u16 As[128 * 32];
  __shared__ __align__(16) u16 Bs[128 * 32];

  const int tid = threadIdx.x;
  int b = blockIdx.z, split = 0;
  if (nsplit > 1) { split = b % nsplit; b /= nsplit; }
  const int m0  = blockIdx.y * 128;
  const int n0  = blockIdx.x * 128;
  const int lane = tid & 63, wave = tid >> 6;
  const int wm = wave >> 1, wn = wave & 1;
  const int lr = lane & 15, lc = lane >> 4;

  f32x4 acc[4][4];
#pragma unroll
  for (int i = 0; i < 4; ++i)
#pragma unroll
    for (int j = 0; j < 4; ++j) acc[i][j] = f32x4{0.f, 0.f, 0.f, 0.f};

  const u16* Ab = A + (int64_t)b * aBatch + split * kStep;
  const u16* Bb = B + (int64_t)b * bBatch + split * kStep;

  const int srow = tid >> 2;
  const int sc   = tid & 3;
  const int scs  = sc ^ (srow & 3);

  for (int kc = 0; kc < 512; kc += 32) {
#pragma unroll
    for (int it = 0; it < 2; ++it) {
      int row = srow + it * 64;
      GLOAD16(Ab + (int64_t)(m0 + row) * sA + kc + scs * 8,
              &As[wave * 512 + it * 2048]);
      GLOAD16(Bb + (int64_t)(n0 + row) * sB + kc + scs * 8,
              &Bs[wave * 512 + it * 2048]);
    }
    __syncthreads();

    bf16x8 af[4], bfr[4];
#pragma unroll
    for (int mf = 0; mf < 4; ++mf) {
      int row = wm * 64 + mf * 16 + lr;
      af[mf] = *(const bf16x8*)&As[row * 32 + ((lc ^ (row & 3)) * 8)];
    }
#pragma unroll
    for (int nf = 0; nf < 4; ++nf) {
      int row = wn * 64 + nf * 16 + lr;
      bfr[nf] = *(const bf16x8*)&Bs[row * 32 + ((lc ^ (row & 3)) * 8)];
    }
#pragma unroll
    for (int mf = 0; mf < 4; ++mf)
#pragma unroll
      for (int nf = 0; nf < 4; ++nf)
        acc[mf][nf] = __builtin_amdgcn_mfma_f32_16x16x32_bf16(af[mf], bfr[nf], acc[mf][nf], 0, 0, 0);
    __syncthreads();
  }

#pragma unroll
  for (int mf = 0; mf < 4; ++mf)
#pragma unroll
    for (int nf = 0; nf < 4; ++nf) {
      f32x4 v = acc[mf][nf];
      int m = m0 + wm * 64 + mf * 16 + lc * 4;
      int n = n0 + wn * 64 + nf * 16 + lr;
      float* p = orm + splitOut * split + rmBatch * b + (int64_t)m * rmStride + n;
#pragma unroll
      for (int r = 0; r < 4; ++r) p[(int64_t)r * rmStride] = v[r];
    }
}

// ===========================================================================
// k_tail: fused y = mattn@v -> gate = Wg@[y;x], res = Wr@x, sigmoid blend.
// ===========================================================================
__global__ __launch_bounds__(512) void k_tail(
    const u16* __restrict__ mattn, const u16* __restrict__ qkvT,
    const u16* __restrict__ ycatT, const u16* __restrict__ Wg,
    const u16* __restrict__ Wr, float* __restrict__ out)
{
  __shared__ __align__(16) u16 As[256 * 32];    // 16 KB (mattn / Wg slices)
  __shared__ __align__(16) u16 As2[256 * 32];   // 16 KB (Wr slices)
  __shared__ __align__(16) u16 Bs[128 * 32];    // 8 KB  (v / x slices)
  __shared__ __align__(16) u16 yT[128 * 260];   // 65 KB (y^T, padded)

  const int b = blockIdx.y, l0 = blockIdx.x * 128;
  const int tid = threadIdx.x;
  const int lane = tid & 63, wave = tid >> 6;
  const int wm = wave >> 1, wn = wave & 1;      // 4M x 2N (wm 0..3)
  const int lr = lane & 15, lc = lane >> 4;

  const int srow = tid >> 2, sc = tid & 3;      // staging row/chunk
  const int scs = sc ^ (srow & 3);

  f32x4 acc[4][4];
#pragma unroll
  for (int i = 0; i < 4; ++i)
#pragma unroll
    for (int j = 0; j < 4; ++j) acc[i][j] = f32x4{0.f, 0.f, 0.f, 0.f};

  // ---- phase 1: y[256][128] = mattn @ v ----
  const u16* Am = mattn + (int64_t)b * 65536;
  const u16* Vv = qkvT + (int64_t)b * 4096 * 768 + 512;
  for (int kc = 0; kc < 256; kc += 32) {
#pragma unroll
    for (int it = 0; it < 2; ++it) {
      int row = srow + it * 128;
      GLOAD16(Am + (int64_t)row * 256 + kc + scs * 8,
              &As[wave * 512 + it * 4096]);
    }
    GLOAD16(Vv + (int64_t)(l0 + srow) * 768 + kc + scs * 8, &Bs[wave * 512]);
    __syncthreads();

    bf16x8 af[4], bfr[4];
#pragma unroll
    for (int mf = 0; mf < 4; ++mf) {
      int row = wm * 64 + mf * 16 + lr;
      af[mf] = *(const bf16x8*)&As[row * 32 + ((lc ^ (row & 3)) * 8)];
    }
#pragma unroll
    for (int nf = 0; nf < 4; ++nf) {
      int row = wn * 64 + nf * 16 + lr;
      bfr[nf] = *(const bf16x8*)&Bs[row * 32 + ((lc ^ (row & 3)) * 8)];
    }
#pragma unroll
    for (int mf = 0; mf < 4; ++mf)
#pragma unroll
      for (int nf = 0; nf < 4; ++nf)
        acc[mf][nf] = __builtin_amdgcn_mfma_f32_16x16x32_bf16(af[mf], bfr[nf], acc[mf][nf], 0, 0, 0);
    __syncthreads();
  }

  // transpose y into LDS: yT[l_local][ch] bf16 (padded stride 260)
#pragma unroll
  for (int mf = 0; mf < 4; ++mf)
#pragma unroll
    for (int nf = 0; nf < 4; ++nf) {
      f32x4 v = acc[mf][nf];
      int m = wm * 64 + mf * 16 + lc * 4;
      int n = wn * 64 + nf * 16 + lr;
      U16x4 pk{f2bf(v[0]), f2bf(v[1]), f2bf(v[2]), f2bf(v[3])};
      *(U16x4*)&yT[n * 260 + m] = pk;
    }
  __syncthreads();

  // ---- phase 2: gate (K=512) + res (K 256..511), dual accumulators ----
  f32x4 acc2[4][4];
#pragma unroll
  for (int i = 0; i < 4; ++i)
#pragma unroll
    for (int j = 0; j < 4; ++j) {
      acc[i][j] = f32x4{0.f, 0.f, 0.f, 0.f};
      acc2[i][j] = f32x4{0.f, 0.f, 0.f, 0.f};
    }

  const u16* Xc = ycatT + (int64_t)b * 4096 * 512;
  for (int kc = 0; kc < 512; kc += 32) {
    const bool xk = (kc >= 256);
#pragma unroll
    for (int it = 0; it < 2; ++it) {
      int row = srow + it * 128;
      GLOAD16(Wg + (int64_t)row * 512 + kc + scs * 8,
              &As[wave * 512 + it * 4096]);
    }
    if (xk) {
#pragma unroll
      for (int it = 0; it < 2; ++it) {
        int row = srow + it * 128;
        GLOAD16(Wr + (int64_t)row * 256 + (kc - 256) + scs * 8,
                &As2[wave * 512 + it * 4096]);
      }
      GLOAD16(Xc + (int64_t)(l0 + srow) * 512 + kc + scs * 8, &Bs[wave * 512]);
    }
    __syncthreads();

    bf16x8 af[4], bfr[4];
#pragma unroll
    for (int nf = 0; nf < 4; ++nf) {
      int row = wn * 64 + nf * 16 + lr;
      if (xk) bfr[nf] = *(const bf16x8*)&Bs[row * 32 + ((lc ^ (row & 3)) * 8)];
      else    bfr[nf] = *(const bf16x8*)&yT[row * 260 + kc + lc * 8];
    }
#pragma unroll
    for (int mf = 0; mf < 4; ++mf) {
      int row = wm * 64 + mf * 16 + lr;
      af[mf] = *(const bf16x8*)&As[row * 32 + ((lc ^ (row & 3)) * 8)];
    }
#pragma unroll
    for (int mf = 0; mf < 4; ++mf)
#pragma unroll
      for (int nf = 0; nf < 4; ++nf)
        acc[mf][nf] = __builtin_amdgcn_mfma_f32_16x16x32_bf16(af[mf], bfr[nf], acc[mf][nf], 0, 0, 0);
    if (xk) {
      bf16x8 af2[4];
#pragma unroll
      for (int mf = 0; mf < 4; ++mf) {
        int row = wm * 64 + mf * 16 + lr;
        af2[mf] = *(const bf16x8*)&As2[row * 32 + ((lc ^ (row & 3)) * 8)];
      }
#pragma unroll
      for (int mf = 0; mf < 4; ++mf)
#pragma unroll
        for (int nf = 0; nf < 4; ++nf)
          acc2[mf][nf] = __builtin_amdgcn_mfma_f32_16x16x32_bf16(af2[mf], bfr[nf], acc2[mf][nf], 0, 0, 0);
    }
    __syncthreads();
  }

  // epilogue: out = sig(gpre)*res + (1-sig)*y
#pragma unroll
  for (int mf = 0; mf < 4; ++mf)
#pragma unroll
    for (int nf = 0; nf < 4; ++nf) {
      f32x4 g4 = acc[mf][nf], r4 = acc2[mf][nf];
      int m = wm * 64 + mf * 16 + lc * 4;
      int n = wn * 64 + nf * 16 + lr;
      U16x4 yv = *(const U16x4*)&yT[n * 260 + m];
      const u16* yp = (const u16*)&yv;
      float* p = out + (int64_t)b * 256 * 4096 + (int64_t)m * 4096 + l0 + n;
#pragma unroll
      for (int r = 0; r < 4; ++r) {
        float g = 1.f / (1.f + __expf(-g4[r]));
        p[(int64_t)r * 4096] = g * r4[r] + (1.f - g) * bf2f(yp[r]);
      }
    }
}

// ---------------------------------------------------------------------------
// merged prep: all weight converts + zero page in ONE kernel
// ---------------------------------------------------------------------------
__global__ void k_prep(const float* __restrict__ wqkv, const float* __restrict__ wmod,
                       const float* __restrict__ wgate, const float* __restrict__ wres,
                       u16* __restrict__ Wa, u16* __restrict__ Wb,
                       u16* __restrict__ Wg, u16* __restrict__ Wr,
                       uint32_t* __restrict__ zpage) {
  int bid = blockIdx.x, t = threadIdx.x;
  if (bid < 6912) {                           // Wa: 768 x (9*256)
    int idx = bid * 256 + t;
    if (idx < 768 * 2304) {
      int oc = idx / 2304, r = idx % 2304;
      int tap = r >> 8, ic = r & 255;
      Wa[idx] = f2bf(wqkv[((oc * 256 + ic) * 3 + tap / 3) * 3 + tap % 3]);
    }
  } else if (bid < 8448) {                    // Wb: 512 x (3*256)
    int idx = (bid - 6912) * 256 + t;
    if (idx < 512 * 768) {
      int oc = idx / 768, r = idx % 768;
      int tap = r >> 8, ic = r & 255;
      Wb[idx] = f2bf(wmod[(oc * 256 + ic) * 3 + tap]);
    }
  } else if (bid < 8960) {                    // Wg: 256 x 512
    int idx = (bid - 8448) * 256 + t;
    if (idx < 131072) Wg[idx] = f2bf(wgate[idx]);
  } else if (bid < 9216) {                    // Wr: 256 x 256
    int idx = (bid - 8960) * 256 + t;
    if (idx < 65536) Wr[idx] = f2bf(wres[idx]);
  } else {
    if (t < 64) zpage[t] = 0u;
  }
}

// ---------------------------------------------------------------------------
// x (B,256,4096) f32 -> ycatT[b][l][256+c] bf16 (x part of concat buffer)
// ---------------------------------------------------------------------------
__global__ __launch_bounds__(256) void k_xT(const float* __restrict__ x, u16* __restrict__ ycat) {
  __shared__ float tile[64 * 68];
  int b = blockIdx.z, c0 = blockIdx.y * 64, l0 = blockIdx.x * 64;
  int t = threadIdx.x;
  int cc = t >> 2, part = t & 3;
  const float* xp = x + ((int64_t)(b * 256 + c0 + cc)) * 4096 + l0 + part * 16;
#pragma unroll
  for (int j = 0; j < 4; ++j) {
    F4 v = *(const F4*)(xp + j * 4);
    float* tp = &tile[cc * 68 + part * 16 + j * 4];
    tp[0] = v.x; tp[1] = v.y; tp[2] = v.z; tp[3] = v.w;
  }
  __syncthreads();
  int l = t >> 2;
  u16* op = ycat + ((int64_t)b * 4096 + l0 + l) * 512 + 256 + c0 + part * 16;
  __align__(16) u16 tmp[16];
#pragma unroll
  for (int j = 0; j < 16; ++j) tmp[j] = f2bf(tile[(part * 16 + j) * 68 + l]);
  *(V16*)(op) = *(V16*)&tmp[0];
  *(V16*)(op + 8) = *(V16*)&tmp[8];
}

// sum 64 partials per channel -> 1/S
__global__ void k_statsB64(const float* __restrict__ part, float* __restrict__ inv) {
  int idx = blockIdx.x * 256 + threadIdx.x;   // 4096 channels (b*512+m)
  float S = 0.f;
#pragma unroll
  for (int s = 0; s < 64; ++s) S += part[(int64_t)idx * 64 + s];
  inv[idx] = 1.0f / S;
}

// softmax over d of (sum split-K partials)*invSq[c]*invSk[d]*(1/16)
__global__ __launch_bounds__(256) void k_softmax_attn(
    const float* __restrict__ sc, const float* __restrict__ invS,
    u16* __restrict__ ma, int nsplit, int64_t splitOff) {
  int c = blockIdx.x, b = blockIdx.y;
  int64_t base = ((int64_t)b * 256 + c) * 256;
  int t = threadIdx.x;
  float z = 0.f;
  for (int s = 0; s < nsplit; ++s) z += sc[(int64_t)s * splitOff + base + t];
  float iq = invS[(int64_t)b * 512 + c];
  float ik = invS[(int64_t)b * 512 + 256 + t];
  z *= iq * ik * 0.0625f;
  __shared__ float red[256];
  red[t] = z; __syncthreads();
  for (int s = 128; s > 0; s >>= 1) { if (t < s) red[t] = fmaxf(red[t], red[t + s]); __syncthreads(); }
  float M = red[0]; __syncthreads();
  float p = __expf(z - M);
  red[t] = p; __syncthreads();
  for (int s = 128; s > 0; s >>= 1) { if (t < s) red[t] += red[t + s]; __syncthreads(); }
  ma[base + t] = f2bf(p / red[0]);
}

// ---------------------------------------------------------------------------
extern "C" void kernel_launch(void* const* d_in, const int* in_sizes, int n_in,
                              void* d_out, int out_size, void* d_ws, size_t ws_size,
                              hipStream_t stream) {
  (void)in_sizes; (void)n_in; (void)out_size; (void)ws_size;
  const float* x      = (const float*)d_in[0];
  const float* w_qkv  = (const float*)d_in[1];
  const float* w_mod  = (const float*)d_in[2];
  const float* w_res  = (const float*)d_in[3];
  const float* w_gate = (const float*)d_in[4];
  float* out = (float*)d_out;

  char* p = (char*)d_ws;
  auto take = [&](size_t n) { void* r = (void*)p; p += (n + 255) & ~(size_t)255; return r; };
  u16*    zpage  = (u16*)take(256);        // zero page for masked conv taps
  u16*    qkvT   = (u16*)take(50331648);   // [b][l][768] bf16 (q|k|v)
  u16*    ycatT  = (u16*)take(33554432);   // [b][l][512] bf16 (x in cols 256+)
  u16*    eT     = (u16*)take(33554432);   // [b][512ch][l] bf16 (e_q|e_k)
  float*  scores = (float*)take(16777216); // [8 splits][b][c][d] f32
  u16*    mattn  = (u16*)take(1048576);    // [b][c][d] bf16
  float*  partS  = (float*)take(1048576);  // [b*512+ch][64] partial sums
  float*  invS   = (float*)take(16384);    // [b*512+ch] 1/S
  u16*    Wa     = (u16*)take(3538944);    // 768 x 2304
  u16*    Wb     = (u16*)take(786432);     // 512 x 768
  u16*    Wg     = (u16*)take(262144);     // 256 x 512
  u16*    Wr     = (u16*)take(131072);     // 256 x 256

  k_prep<<<9217, 256, 0, stream>>>(w_qkv, w_mod, w_gate, w_res,
                                   Wa, Wb, Wg, Wr, (uint32_t*)zpage);
  k_xT<<<dim3(64, 4, 8), 256, 0, stream>>>(x, ycatT);

  // qkv = conv2d(x, w_qkv): M=768 N=4096 K=9*256 -> qkvT bf16
  gemmOv_bf16<2, 6><<<512, 512, 0, stream>>>(
      Wa, ycatT + 256, qkvT,
      2304, 512, (int64_t)4096 * 512,
      768, (int64_t)4096 * 768, 4, zpage);

  // mod = conv1d(v, w_mod) FUSED with e = exp(-relu(q*mod)) -> eT + partS
  gemmOv_bf16<1, 8, 1><<<256, 512, 0, stream>>>(
      Wb, qkvT + 512, nullptr,
      768, 768, (int64_t)4096 * 768,
      0, 0, 2, zpage,
      qkvT, eT, partS);

  k_statsB64<<<16, 256, 0, stream>>>(partS, invS);

  // scores'[c][d] = sum_l e_q[c,l]*e_k[d,l]: M=256 N=256 K=4096, split-K x8
  gemm_scores<<<dim3(2, 2, 64), 256, 0, stream>>>(
      eT, eT + (int64_t)256 * 4096, scores,
      4096, (int64_t)512 * 4096,
      4096, (int64_t)512 * 4096,
      256, (int64_t)256 * 256,
      8, 512, (int64_t)8 * 256 * 256);

  k_softmax_attn<<<dim3(256, 8), 256, 0, stream>>>(
      scores, invS, mattn, 8, (int64_t)8 * 256 * 256);

  // fused tail: y = mattn@v -> gate/res/blend -> out
  k_tail<<<dim3(32, 8), 512, 0, stream>>>(mattn, qkvT, ycatT, Wg, Wr, out);
}